// Round 4
// baseline (708.248 us; speedup 1.0000x reference)
//
#include <hip/hip_runtime.h>
#include <stdint.h>

// R10: inter-block overlap + chain shortening. R9 post-mortem: doubling
// occupancy (22.6->45%) changed nothing because the extra waves were in the
// SAME block (lock-step through barrier phases); latency is hidden by
// INTER-block overlap, which stayed at ~2. Cycle model: per-block critical
// path ~9k cyc (un-prefetched ds_read A-loads ~120cyc/kstep x 24 ksteps +
// barriers + scalar phases), x16 blocks/CU / 2-overlap ~= 72k ~= measured.
// Changes:
//   1. 256-thr / 4-wave blocks (16 acc/wave) at __launch_bounds__(256,3):
//      170-reg budget, 12 waves/CU = 3 blocks/CU overlap (vs 2).
//   2. K-loops: unroll-1 ping-pong double-buffer of BOTH A (LDS) and B (L2),
//      peeled tail. Live ~= acc64 + B32 + A32 + addr25 ~= 150 < 170 -> no
//      spill by construction (R7's 170-spill was full-unroll ~190 hoist).
//      A-prefetch removes ~120cyc/kstep from the serial chain.
//   3. Keep R9 wins: cvtpk epilogues, unroll-1 L1, coalesced pack_weights.
// Tripwire: FETCH ~3MB / WRITE ~0.5MB. Predicted dur ~220-250us.

#define NRAYS 4096

typedef unsigned short u16;
typedef __attribute__((ext_vector_type(8))) short short8;
typedef __attribute__((ext_vector_type(4))) float f32x4;
typedef __attribute__((ext_vector_type(4))) unsigned int uint32x4;

__device__ __forceinline__ u16 f2bf(float f) {
  union { float f; uint32_t i; } v; v.f = f;
  return (u16)((v.i + 0x7FFFu + ((v.i >> 16) & 1u)) >> 16);
}
__device__ __forceinline__ float bf2f(u16 u) {
  union { uint32_t i; float f; } v; v.i = ((uint32_t)u) << 16; return v.f;
}
// packed fp32->bf16 (RNE), lo -> bits 15:0, hi -> bits 31:16
__device__ __forceinline__ uint32_t cvtpk(float lo, float hi) {
  uint32_t r;
  asm("v_cvt_pk_bf16_f32 %0, %1, %2" : "=v"(r) : "v"(lo), "v"(hi));
  return r;
}

// ---------------- weight transpose + fp32->bf16 convert into workspace ----------------
// ws (bf16 elems): W2t [256n][256k] @0, W3t [256n][256k] @65536, W4t [128n][256k] @131072
__global__ void pack_weights(const float* __restrict__ W2, const float* __restrict__ W3,
                             const float* __restrict__ W4, u16* __restrict__ ws) {
  int idx = blockIdx.x * 256 + threadIdx.x;   // grid covers exactly 163840
  float v;
  int dst;
  if (idx < 65536) {
    int k = idx >> 8, n = idx & 255;          // W2 row-major [k][n]
    v = W2[idx];
    dst = n * 256 + k;
  } else if (idx < 131072) {
    int o = idx - 65536, k = o >> 8, n = o & 255;
    v = W3[o];
    dst = 65536 + n * 256 + k;
  } else {
    int o = idx - 131072, k = o >> 7, n = o & 127;  // W4 row-major [k][128]
    v = W4[o];
    dst = 131072 + n * 256 + k;
  }
  ws[dst] = f2bf(v);
}

#define MFMA __builtin_amdgcn_mfma_f32_16x16x32_bf16
#define ZER4 (f32x4){0.f, 0.f, 0.f, 0.f}

// load 4 B columns for k-slice sq into named bufs P0..P3
#define LDB4(P, sq_) do { int s_ = (sq_);                                    \
    P##0 = *(const short8*)(bp0 + s_ * 8);                                   \
    P##1 = *(const short8*)(bp1 + s_ * 8);                                   \
    P##2 = *(const short8*)(bp2 + s_ * 8);                                   \
    P##3 = *(const short8*)(bp3 + s_ * 8); } while (0)
// load 2 B columns (layer 4)
#define LDB2(P, sq_) do { int s_ = (sq_);                                    \
    P##0 = *(const short8*)(bp0 + s_ * 8);                                   \
    P##1 = *(const short8*)(bp1 + s_ * 8); } while (0)
// load 4 A row-tiles for k-slice sq (LDS, XOR-swizzled)
// m0&31==m2&31==l15, m1&31==m3&31==l15+16
#define LDA4(P, sq_) do { int s_ = (sq_);                                    \
    int x0_ = ((s_ ^ l15) << 3), x1_ = ((s_ ^ (l15 + 16)) << 3);             \
    P##0 = *(const short8*)(act + m0 * 256 + x0_);                           \
    P##1 = *(const short8*)(act + m1 * 256 + x1_);                           \
    P##2 = *(const short8*)(act + m2 * 256 + x0_);                           \
    P##3 = *(const short8*)(act + m3 * 256 + x1_); } while (0)

// 16 MFMA on buffers BB (B cols 0..3) x AA (A row-tiles 0..3)
#define MF16(BB, AA) do {                                                    \
    c00 = MFMA(AA##0, BB##0, c00, 0, 0, 0); c10 = MFMA(AA##1, BB##0, c10, 0, 0, 0); \
    c20 = MFMA(AA##2, BB##0, c20, 0, 0, 0); c30 = MFMA(AA##3, BB##0, c30, 0, 0, 0); \
    c01 = MFMA(AA##0, BB##1, c01, 0, 0, 0); c11 = MFMA(AA##1, BB##1, c11, 0, 0, 0); \
    c21 = MFMA(AA##2, BB##1, c21, 0, 0, 0); c31 = MFMA(AA##3, BB##1, c31, 0, 0, 0); \
    c02 = MFMA(AA##0, BB##2, c02, 0, 0, 0); c12 = MFMA(AA##1, BB##2, c12, 0, 0, 0); \
    c22 = MFMA(AA##2, BB##2, c22, 0, 0, 0); c32 = MFMA(AA##3, BB##2, c32, 0, 0, 0); \
    c03 = MFMA(AA##0, BB##3, c03, 0, 0, 0); c13 = MFMA(AA##1, BB##3, c13, 0, 0, 0); \
    c23 = MFMA(AA##2, BB##3, c23, 0, 0, 0); c33 = MFMA(AA##3, BB##3, c33, 0, 0, 0); \
  } while (0)

// 8 MFMA on buffers BB (B cols 0..1) x AA (layer 4)
#define MF8(BB, AA) do {                                                     \
    c00 = MFMA(AA##0, BB##0, c00, 0, 0, 0); c10 = MFMA(AA##1, BB##0, c10, 0, 0, 0); \
    c20 = MFMA(AA##2, BB##0, c20, 0, 0, 0); c30 = MFMA(AA##3, BB##0, c30, 0, 0, 0); \
    c01 = MFMA(AA##0, BB##1, c01, 0, 0, 0); c11 = MFMA(AA##1, BB##1, c11, 0, 0, 0); \
    c21 = MFMA(AA##2, BB##1, c21, 0, 0, 0); c31 = MFMA(AA##3, BB##1, c31, 0, 0, 0); \
  } while (0)

// store one 16x16 C-tile (f32x4 CV), row-tile mt, column ng, into swizzled act
// (packed bf16 convert: 2 x v_cvt_pk_bf16_f32, bit-identical to f2bf RNE)
#define EPIC(CV, mt, ng, addv) do {                                          \
    int su_ = ((ng) >> 3), so_ = ((ng) & 7);                                 \
    float f0_ = fmaxf((CV)[0] + (addv), 0.f);                                \
    float f1_ = fmaxf((CV)[1] + (addv), 0.f);                                \
    float f2_ = fmaxf((CV)[2] + (addv), 0.f);                                \
    float f3_ = fmaxf((CV)[3] + (addv), 0.f);                                \
    uint32_t p01_ = cvtpk(f0_, f1_), p23_ = cvtpk(f2_, f3_);                 \
    int mmb_ = (mt) * 16 + quad * 4;                                         \
    act[(mmb_ + 0) * 256 + ((su_ ^ ((mmb_ + 0) & 31)) << 3) + so_] = (u16)p01_;         \
    act[(mmb_ + 1) * 256 + ((su_ ^ ((mmb_ + 1) & 31)) << 3) + so_] = (u16)(p01_ >> 16); \
    act[(mmb_ + 2) * 256 + ((su_ ^ ((mmb_ + 2) & 31)) << 3) + so_] = (u16)p23_;         \
    act[(mmb_ + 3) * 256 + ((su_ ^ ((mmb_ + 3) & 31)) << 3) + so_] = (u16)(p23_ >> 16); \
  } while (0)

__global__ void __launch_bounds__(256, 3) nerf_fused(
    const float* __restrict__ rays_o, const float* __restrict__ rays_d,
    const float* __restrict__ t_rand,
    const float* __restrict__ W1, const float* __restrict__ b1,
    const float* __restrict__ b2, const float* __restrict__ b3,
    const float* __restrict__ Wd, const float* __restrict__ bd,
    const float* __restrict__ W4, const float* __restrict__ b4,
    const float* __restrict__ W5, const float* __restrict__ b5,
    const u16* __restrict__ wpack, float* __restrict__ out) {
  __shared__ u16   act[64 * 256];    // 32 KB, XOR-swizzled slots
  __shared__ float zv[64];
  __shared__ float dist[64];
  __shared__ float dens[64];
  __shared__ float rgbL[64 * 4];
  __shared__ float vdirL[4];
  __shared__ float w5L[384];
  __shared__ float b5L[4];

  const int t = threadIdx.x;
  const int lane = t & 63;
  const int wv = t >> 6;        // 0..3
  const int quad = lane >> 4;
  const int l15 = lane & 15;
  const int ray = blockIdx.x;
  const int m0 = l15, m1 = l15 + 16, m2 = l15 + 32, m3 = l15 + 48;

  // ---- setup ----
  if (t < 64) {
    int j = t;
    float fj = (float)j;
    float zj = 0.5f + 2.0f * (fj / 63.0f);
    float lower = (j == 0)  ? zj : 0.5f * (zj + (0.5f + 2.0f * ((fj - 1.0f) / 63.0f)));
    float upper = (j == 63) ? zj : 0.5f * (zj + (0.5f + 2.0f * ((fj + 1.0f) / 63.0f)));
    float tr = t_rand[ray * 64 + j];
    zv[j] = lower + (upper - lower) * tr;
  } else {
    int idx = t - 64;                 // 0..191
    w5L[idx] = W5[idx];
    w5L[idx + 192] = W5[idx + 192];
  }
  if (t < 3) b5L[t] = b5[t];
  if (t == 0) {
    float dx = rays_d[ray * 3 + 0];
    float dy = rays_d[ray * 3 + 1];
    float dz = rays_d[ray * 3 + 2];
    float nrm = sqrtf(dx * dx + dy * dy + dz * dz) + 1e-8f;
    vdirL[0] = dx / nrm; vdirL[1] = dy / nrm; vdirL[2] = dz / nrm;
  }
  __syncthreads();

  if (t < 64) dist[t] = (t < 63) ? (zv[t + 1] - zv[t]) : 1e10f;

  // ---- layer 1: h1 = relu(pts@W1 + b1) -> act (unroll-1: bounded liveness) ----
  {
    int m = t >> 2, p = t & 3;
    float zm = zv[m];
    float px = rays_o[ray * 3 + 0] + rays_d[ray * 3 + 0] * zm;
    float py = rays_o[ray * 3 + 1] + rays_d[ray * 3 + 1] * zm;
    float pz = rays_o[ray * 3 + 2] + rays_d[ray * 3 + 2] * zm;
#pragma unroll 1
    for (int kk = 0; kk < 64; kk += 8) {
      int k0 = p * 64 + kk;
      f32x4 bva = *(const f32x4*)(b1 + k0);
      f32x4 bvb = *(const f32x4*)(b1 + k0 + 4);
      f32x4 w0a = *(const f32x4*)(W1 + k0);
      f32x4 w0b = *(const f32x4*)(W1 + k0 + 4);
      f32x4 w1a = *(const f32x4*)(W1 + 256 + k0);
      f32x4 w1b = *(const f32x4*)(W1 + 256 + k0 + 4);
      f32x4 w2a = *(const f32x4*)(W1 + 512 + k0);
      f32x4 w2b = *(const f32x4*)(W1 + 512 + k0 + 4);
      f32x4 sa = bva + px * w0a + py * w1a + pz * w2a;
      f32x4 sb = bvb + px * w0b + py * w1b + pz * w2b;
      uint32x4 pk;
      pk[0] = cvtpk(fmaxf(sa[0], 0.f), fmaxf(sa[1], 0.f));
      pk[1] = cvtpk(fmaxf(sa[2], 0.f), fmaxf(sa[3], 0.f));
      pk[2] = cvtpk(fmaxf(sb[0], 0.f), fmaxf(sb[1], 0.f));
      pk[3] = cvtpk(fmaxf(sb[2], 0.f), fmaxf(sb[3], 0.f));
      int u = (k0 >> 3) ^ (m & 31);
      *(uint32x4*)(act + m * 256 + u * 8) = pk;
    }
  }
  __syncthreads();

  // ---- layers 2 & 3: h = relu(h@W + b), K=256, N=256 ----
  // 4 waves, wave owns 64 cols: 16 acc. unroll-1 ping-pong A+B double buffer.
#pragma unroll 1
  for (int L = 0; L < 2; L++) {
    const u16* wB = wpack + L * 65536;
    const float* bb = (L == 0) ? b2 : b3;
    const u16* bp0 = wB + (wv * 64 +  0 + l15) * 256;
    const u16* bp1 = wB + (wv * 64 + 16 + l15) * 256;
    const u16* bp2 = wB + (wv * 64 + 32 + l15) * 256;
    const u16* bp3 = wB + (wv * 64 + 48 + l15) * 256;
    f32x4 c00 = ZER4, c01 = ZER4, c02 = ZER4, c03 = ZER4;
    f32x4 c10 = ZER4, c11 = ZER4, c12 = ZER4, c13 = ZER4;
    f32x4 c20 = ZER4, c21 = ZER4, c22 = ZER4, c23 = ZER4;
    f32x4 c30 = ZER4, c31 = ZER4, c32 = ZER4, c33 = ZER4;
    short8 ba0, ba1, ba2, ba3, bb0, bb1, bb2, bb3;
    short8 aa0, aa1, aa2, aa3, ab0, ab1, ab2, ab3;
    LDB4(ba, quad);            // k-step 0
    LDA4(aa, quad);
#pragma unroll 1
    for (int kc = 0; kc < 3; kc++) {
      int sqB = (2 * kc + 1) * 4 + quad;
      LDB4(bb, sqB); LDA4(ab, sqB);       // prefetch odd step
      MF16(ba, aa);                       // compute even step
      int sqA = (2 * kc + 2) * 4 + quad;
      LDB4(ba, sqA); LDA4(aa, sqA);       // prefetch next even step
      MF16(bb, ab);                       // compute odd step
    }
    LDB4(bb, 28 + quad); LDA4(ab, 28 + quad);  // k-step 7
    MF16(ba, aa);                              // k-step 6
    MF16(bb, ab);                              // k-step 7
    __syncthreads();               // all act reads done before in-place rewrite
    {
      int ng0 = wv * 64 + l15;
      float bi0 = bb[ng0], bi1 = bb[ng0 + 16], bi2 = bb[ng0 + 32], bi3 = bb[ng0 + 48];
      EPIC(c00, 0, ng0, bi0); EPIC(c10, 1, ng0, bi0);
      EPIC(c20, 2, ng0, bi0); EPIC(c30, 3, ng0, bi0);
      EPIC(c01, 0, ng0 + 16, bi1); EPIC(c11, 1, ng0 + 16, bi1);
      EPIC(c21, 2, ng0 + 16, bi1); EPIC(c31, 3, ng0 + 16, bi1);
      EPIC(c02, 0, ng0 + 32, bi2); EPIC(c12, 1, ng0 + 32, bi2);
      EPIC(c22, 2, ng0 + 32, bi2); EPIC(c32, 3, ng0 + 32, bi2);
      EPIC(c03, 0, ng0 + 48, bi3); EPIC(c13, 1, ng0 + 48, bi3);
      EPIC(c23, 2, ng0 + 48, bi3); EPIC(c33, 3, ng0 + 48, bi3);
    }
    __syncthreads();
  }

  // ---- density: fp32 dot(h3, Wd) ----
  {
    int m = t >> 2, p = t & 3;
    float s = 0.f;
#pragma unroll
    for (int kk = 0; kk < 64; kk += 8) {
      int k0 = p * 64 + kk;
      short8 h = *(const short8*)(act + m * 256 + (((k0 >> 3) ^ (m & 31)) << 3));
      f32x4 wa = *(const f32x4*)(Wd + k0);
      f32x4 wb = *(const f32x4*)(Wd + k0 + 4);
      s += bf2f((u16)h[0]) * wa[0] + bf2f((u16)h[1]) * wa[1]
         + bf2f((u16)h[2]) * wa[2] + bf2f((u16)h[3]) * wa[3]
         + bf2f((u16)h[4]) * wb[0] + bf2f((u16)h[5]) * wb[1]
         + bf2f((u16)h[6]) * wb[2] + bf2f((u16)h[7]) * wb[3];
    }
    s += __shfl_xor(s, 1);
    s += __shfl_xor(s, 2);
    if (p == 0) dens[m] = s + bd[0];
  }

  // ---- layer 4: h4 = relu(h3@W4[:256] + vdir@W4[256:259] + b4), N=128 ----
  // 4 waves, wave owns 32 cols: 8 acc. Same ping-pong structure.
  {
    const u16* wB = wpack + 131072;
    const u16* bp0 = wB + (wv * 32 +  0 + l15) * 256;
    const u16* bp1 = wB + (wv * 32 + 16 + l15) * 256;
    f32x4 c00 = ZER4, c01 = ZER4;
    f32x4 c10 = ZER4, c11 = ZER4;
    f32x4 c20 = ZER4, c21 = ZER4;
    f32x4 c30 = ZER4, c31 = ZER4;
    short8 ba0, ba1, bb0, bb1;
    short8 aa0, aa1, aa2, aa3, ab0, ab1, ab2, ab3;
    LDB2(ba, quad);
    LDA4(aa, quad);
#pragma unroll 1
    for (int kc = 0; kc < 3; kc++) {
      int sqB = (2 * kc + 1) * 4 + quad;
      LDB2(bb, sqB); LDA4(ab, sqB);
      MF8(ba, aa);
      int sqA = (2 * kc + 2) * 4 + quad;
      LDB2(ba, sqA); LDA4(aa, sqA);
      MF8(bb, ab);
    }
    LDB2(bb, 28 + quad); LDA4(ab, 28 + quad);
    MF8(ba, aa);
    MF8(bb, ab);
    __syncthreads();               // all h3 reads done (incl. density) before rewrite
    {
      float v0 = vdirL[0], v1 = vdirL[1], v2 = vdirL[2];
      int ng0 = wv * 32 + l15;
      float ad0 = b4[ng0] + v0 * W4[32768 + ng0] + v1 * W4[32896 + ng0] + v2 * W4[33024 + ng0];
      int ng1 = ng0 + 16;
      float ad1 = b4[ng1] + v0 * W4[32768 + ng1] + v1 * W4[32896 + ng1] + v2 * W4[33024 + ng1];
      EPIC(c00, 0, ng0, ad0); EPIC(c10, 1, ng0, ad0);
      EPIC(c20, 2, ng0, ad0); EPIC(c30, 3, ng0, ad0);
      EPIC(c01, 0, ng1, ad1); EPIC(c11, 1, ng1, ad1);
      EPIC(c21, 2, ng1, ad1); EPIC(c31, 3, ng1, ad1);
    }
  }
  __syncthreads();

  // ---- rgb = sigmoid(h4@W5 + b5) ----
  {
    int m = t >> 2, p = t & 3;
    float s0 = 0.f, s1 = 0.f, s2 = 0.f;
#pragma unroll
    for (int kk = 0; kk < 32; kk += 8) {
      int k0 = p * 32 + kk;
      short8 h = *(const short8*)(act + m * 256 + (((k0 >> 3) ^ (m & 31)) << 3));
#pragma unroll
      for (int j = 0; j < 8; j++) {
        float hv = bf2f((u16)h[j]);
        int k = k0 + j;
        s0 += hv * w5L[k * 3 + 0];
        s1 += hv * w5L[k * 3 + 1];
        s2 += hv * w5L[k * 3 + 2];
      }
    }
    s0 += __shfl_xor(s0, 1); s0 += __shfl_xor(s0, 2);
    s1 += __shfl_xor(s1, 1); s1 += __shfl_xor(s1, 2);
    s2 += __shfl_xor(s2, 1); s2 += __shfl_xor(s2, 2);
    if (p == 0) {
      rgbL[m * 4 + 0] = 1.f / (1.f + __expf(-(s0 + b5L[0])));
      rgbL[m * 4 + 1] = 1.f / (1.f + __expf(-(s1 + b5L[1])));
      rgbL[m * 4 + 2] = 1.f / (1.f + __expf(-(s2 + b5L[2])));
    }
  }
  __syncthreads();

  // ---- alpha compositing: wave 0 handles the block's single ray ----
  if (t < 64) {
    int j = t;
    float alpha = 1.f - __expf(-fmaxf(dens[j], 0.f) * dist[j]);
    float v = 1.f - alpha + 1e-10f;
    float pscan = v;
#pragma unroll
    for (int d = 1; d < 64; d <<= 1) {
      float o = __shfl_up(pscan, d);
      if (j >= d) pscan *= o;
    }
    float T = __shfl_up(pscan, 1);
    if (j == 0) T = 1.f;
    float w = alpha * T;
    float r0 = w * rgbL[j * 4 + 0];
    float r1 = w * rgbL[j * 4 + 1];
    float r2 = w * rgbL[j * 4 + 2];
    float dp = w * zv[j];
    float ac = w;
#pragma unroll
    for (int d = 32; d; d >>= 1) {
      r0 += __shfl_down(r0, d);
      r1 += __shfl_down(r1, d);
      r2 += __shfl_down(r2, d);
      dp += __shfl_down(dp, d);
      ac += __shfl_down(ac, d);
    }
    if (j == 0) {
      float bg = 1.f - ac;
      out[ray * 3 + 0] = r0 + bg;
      out[ray * 3 + 1] = r1 + bg;
      out[ray * 3 + 2] = r2 + bg;
      out[NRAYS * 3 + ray] = dp;
      out[NRAYS * 4 + ray] = ac;
    }
  }
}

extern "C" void kernel_launch(void* const* d_in, const int* in_sizes, int n_in,
                              void* d_out, int out_size, void* d_ws, size_t ws_size,
                              hipStream_t stream) {
  const float* rays_o = (const float*)d_in[0];
  const float* rays_d = (const float*)d_in[1];
  const float* t_rand = (const float*)d_in[2];
  const float* W1 = (const float*)d_in[3];
  const float* b1 = (const float*)d_in[4];
  const float* W2 = (const float*)d_in[5];
  const float* b2 = (const float*)d_in[6];
  const float* W3 = (const float*)d_in[7];
  const float* b3 = (const float*)d_in[8];
  const float* Wd = (const float*)d_in[9];
  const float* bd = (const float*)d_in[10];
  const float* W4 = (const float*)d_in[11];
  const float* b4 = (const float*)d_in[12];
  const float* W5 = (const float*)d_in[13];
  const float* b5 = (const float*)d_in[14];
  u16* wpack = (u16*)d_ws;
  float* out = (float*)d_out;

  pack_weights<<<640, 256, 0, stream>>>(W2, W3, W4, wpack);
  nerf_fused<<<NRAYS, 256, 0, stream>>>(rays_o, rays_d, t_rand, W1, b1, b2, b3,
                                        Wd, bd, W4, b4, W5, b5, wpack, out);
}

// Round 5
// 304.824 us; speedup vs baseline: 2.3235x; 2.3235x over previous
//
#include <hip/hip_runtime.h>
#include <stdint.h>

// R11: back to the PROVEN no-spill envelope (R6: 256 thr, (256,2), 16 acc,
// full unroll; 331us) and attack per-phase serial chains, not occupancy.
// R7-R10 post-mortem: 16-acc + any double-buffer needs ~192 regs -> spills at
// any budget < 256; occupancy family maxes at 50% (R9) for <=12% gain. All
// pipes idle -> blocks sit in serial phase stalls.
// Changes vs R6:
//   1. Fragment-contiguous B layout: wpack reordered to [nt][kq][lane][8] so
//      each wave B-load is 1KB CONTIGUOUS (8 lines) instead of a 16-line
//      gather (16 x 512B-strided rows). Halves L2 transactions per K-step,
//      simpler addressing (base + kq*1024B literal offsets).
//   2. Density fused into L3 epilogue: h3 is already in regs post-relu;
//      dp[16] += f*Wd[ng], shfl-reduce over l15-group, atomicAdd into dens[].
//      Removes the whole density phase (LDS re-reads + Wd loads + chain).
//   3. Keep cvtpk converts + coalesced pack reads.
// Tripwire: FETCH<=4MB WRITE<=1MB (envelope must stay spill-free), occ ~22.6%.
// Predict dur 331 -> 260-300us. If >=315 clean: phase-serialization floor ->
// pivot to multi-ray persistent blocks next.

#define NRAYS 4096

typedef unsigned short u16;
typedef __attribute__((ext_vector_type(8))) short short8;
typedef __attribute__((ext_vector_type(4))) float f32x4;
typedef __attribute__((ext_vector_type(4))) unsigned int uint32x4;

__device__ __forceinline__ u16 f2bf(float f) {
  union { float f; uint32_t i; } v; v.f = f;
  return (u16)((v.i + 0x7FFFu + ((v.i >> 16) & 1u)) >> 16);
}
__device__ __forceinline__ float bf2f(u16 u) {
  union { uint32_t i; float f; } v; v.i = ((uint32_t)u) << 16; return v.f;
}
// packed fp32->bf16 (RNE), lo -> bits 15:0, hi -> bits 31:16 (bit-identical to f2bf)
__device__ __forceinline__ uint32_t cvtpk(float lo, float hi) {
  uint32_t r;
  asm("v_cvt_pk_bf16_f32 %0, %1, %2" : "=v"(r) : "v"(lo), "v"(hi));
  return r;
}

// fragment-contiguous index for W^T: element (n, k) of a [N][K=256] tile ->
// block (nt = n>>4, kq = k>>5), lane = ((k>>3)&3)*16 + (n&15), elem j = k&7.
// Wave load at (nt,kq) = 64 lanes x 16B = 1KB contiguous.
__device__ __forceinline__ int fragidx(int n, int k) {
  return ((((n >> 4) * 8 + (k >> 5)) * 64 + ((k >> 3) & 3) * 16 + (n & 15)) << 3) + (k & 7);
}

// ---------------- weight transpose + fp32->bf16 convert into workspace ----------------
// ws (bf16 elems): W2f @0 (65536), W3f @65536, W4f @131072 (32768)
// Reads coalesced (v = W[idx]); fragment scatter on the store side.
__global__ void pack_weights(const float* __restrict__ W2, const float* __restrict__ W3,
                             const float* __restrict__ W4, u16* __restrict__ ws) {
  int idx = blockIdx.x * 256 + threadIdx.x;   // grid covers exactly 163840
  float v;
  int dst;
  if (idx < 65536) {
    int k = idx >> 8, n = idx & 255;          // W2 row-major [k][n]
    v = W2[idx];
    dst = fragidx(n, k);
  } else if (idx < 131072) {
    int o = idx - 65536, k = o >> 8, n = o & 255;
    v = W3[o];
    dst = 65536 + fragidx(n, k);
  } else {
    int o = idx - 131072, k = o >> 7, n = o & 127;  // W4 row-major [k][128]
    v = W4[o];
    dst = 131072 + fragidx(n, k);
  }
  ws[dst] = f2bf(v);
}

#define MFMA __builtin_amdgcn_mfma_f32_16x16x32_bf16
#define ZER4 (f32x4){0.f, 0.f, 0.f, 0.f}

// one K-step (kq = 0..7) of the 4-col-tile GEMM: 4 B bursts (1KB each), 4 A
// LDS reads, 16 MFMA. bc0..bc3 = per-col-tile fragment bases (+lane*8).
#define KSTEP4(kq_) do {                                                     \
    const int kq = (kq_);                                                    \
    short8 bv0 = *(const short8*)(bc0 + kq * 512);                           \
    short8 bv1 = *(const short8*)(bc1 + kq * 512);                           \
    short8 bv2 = *(const short8*)(bc2 + kq * 512);                           \
    short8 bv3 = *(const short8*)(bc3 + kq * 512);                           \
    const int sq = kq * 4 + quad;                                            \
    short8 av0 = *(const short8*)(act + m0 * 256 + ((sq ^ (m0 & 31)) << 3)); \
    short8 av1 = *(const short8*)(act + m1 * 256 + ((sq ^ (m1 & 31)) << 3)); \
    short8 av2 = *(const short8*)(act + m2 * 256 + ((sq ^ (m2 & 31)) << 3)); \
    short8 av3 = *(const short8*)(act + m3 * 256 + ((sq ^ (m3 & 31)) << 3)); \
    c00 = MFMA(av0, bv0, c00, 0, 0, 0); c10 = MFMA(av1, bv0, c10, 0, 0, 0);  \
    c20 = MFMA(av2, bv0, c20, 0, 0, 0); c30 = MFMA(av3, bv0, c30, 0, 0, 0);  \
    c01 = MFMA(av0, bv1, c01, 0, 0, 0); c11 = MFMA(av1, bv1, c11, 0, 0, 0);  \
    c21 = MFMA(av2, bv1, c21, 0, 0, 0); c31 = MFMA(av3, bv1, c31, 0, 0, 0);  \
    c02 = MFMA(av0, bv2, c02, 0, 0, 0); c12 = MFMA(av1, bv2, c12, 0, 0, 0);  \
    c22 = MFMA(av2, bv2, c22, 0, 0, 0); c32 = MFMA(av3, bv2, c32, 0, 0, 0);  \
    c03 = MFMA(av0, bv3, c03, 0, 0, 0); c13 = MFMA(av1, bv3, c13, 0, 0, 0);  \
    c23 = MFMA(av2, bv3, c23, 0, 0, 0); c33 = MFMA(av3, bv3, c33, 0, 0, 0);  \
  } while (0)

// one K-step of the 2-col-tile GEMM (layer 4)
#define KSTEP2(kq_) do {                                                     \
    const int kq = (kq_);                                                    \
    short8 bv0 = *(const short8*)(bc0 + kq * 512);                           \
    short8 bv1 = *(const short8*)(bc1 + kq * 512);                           \
    const int sq = kq * 4 + quad;                                            \
    short8 av0 = *(const short8*)(act + m0 * 256 + ((sq ^ (m0 & 31)) << 3)); \
    short8 av1 = *(const short8*)(act + m1 * 256 + ((sq ^ (m1 & 31)) << 3)); \
    short8 av2 = *(const short8*)(act + m2 * 256 + ((sq ^ (m2 & 31)) << 3)); \
    short8 av3 = *(const short8*)(act + m3 * 256 + ((sq ^ (m3 & 31)) << 3)); \
    c00 = MFMA(av0, bv0, c00, 0, 0, 0); c10 = MFMA(av1, bv0, c10, 0, 0, 0);  \
    c20 = MFMA(av2, bv0, c20, 0, 0, 0); c30 = MFMA(av3, bv0, c30, 0, 0, 0);  \
    c01 = MFMA(av0, bv1, c01, 0, 0, 0); c11 = MFMA(av1, bv1, c11, 0, 0, 0);  \
    c21 = MFMA(av2, bv1, c21, 0, 0, 0); c31 = MFMA(av3, bv1, c31, 0, 0, 0);  \
  } while (0)

// store one 16x16 C-tile (f32x4 CV), row-tile mt, column ng, into swizzled act
#define EPIC(CV, mt, ng, addv) do {                                          \
    int su_ = ((ng) >> 3), so_ = ((ng) & 7);                                 \
    float f0_ = fmaxf((CV)[0] + (addv), 0.f);                                \
    float f1_ = fmaxf((CV)[1] + (addv), 0.f);                                \
    float f2_ = fmaxf((CV)[2] + (addv), 0.f);                                \
    float f3_ = fmaxf((CV)[3] + (addv), 0.f);                                \
    uint32_t p01_ = cvtpk(f0_, f1_), p23_ = cvtpk(f2_, f3_);                 \
    int mmb_ = (mt) * 16 + quad * 4;                                         \
    act[(mmb_ + 0) * 256 + ((su_ ^ ((mmb_ + 0) & 31)) << 3) + so_] = (u16)p01_;         \
    act[(mmb_ + 1) * 256 + ((su_ ^ ((mmb_ + 1) & 31)) << 3) + so_] = (u16)(p01_ >> 16); \
    act[(mmb_ + 2) * 256 + ((su_ ^ ((mmb_ + 2) & 31)) << 3) + so_] = (u16)p23_;         \
    act[(mmb_ + 3) * 256 + ((su_ ^ ((mmb_ + 3) & 31)) << 3) + so_] = (u16)(p23_ >> 16); \
  } while (0)

// EPIC + density partial accumulate: dp[mt*4+r] += relu(c+b) * Wd[ng]
#define EPICD(CV, mt, ng, addv, wdv) do {                                    \
    int su_ = ((ng) >> 3), so_ = ((ng) & 7);                                 \
    float f0_ = fmaxf((CV)[0] + (addv), 0.f);                                \
    float f1_ = fmaxf((CV)[1] + (addv), 0.f);                                \
    float f2_ = fmaxf((CV)[2] + (addv), 0.f);                                \
    float f3_ = fmaxf((CV)[3] + (addv), 0.f);                                \
    dp[(mt) * 4 + 0] += f0_ * (wdv);                                         \
    dp[(mt) * 4 + 1] += f1_ * (wdv);                                         \
    dp[(mt) * 4 + 2] += f2_ * (wdv);                                         \
    dp[(mt) * 4 + 3] += f3_ * (wdv);                                         \
    uint32_t p01_ = cvtpk(f0_, f1_), p23_ = cvtpk(f2_, f3_);                 \
    int mmb_ = (mt) * 16 + quad * 4;                                         \
    act[(mmb_ + 0) * 256 + ((su_ ^ ((mmb_ + 0) & 31)) << 3) + so_] = (u16)p01_;         \
    act[(mmb_ + 1) * 256 + ((su_ ^ ((mmb_ + 1) & 31)) << 3) + so_] = (u16)(p01_ >> 16); \
    act[(mmb_ + 2) * 256 + ((su_ ^ ((mmb_ + 2) & 31)) << 3) + so_] = (u16)p23_;         \
    act[(mmb_ + 3) * 256 + ((su_ ^ ((mmb_ + 3) & 31)) << 3) + so_] = (u16)(p23_ >> 16); \
  } while (0)

__global__ void __launch_bounds__(256, 2) nerf_fused(
    const float* __restrict__ rays_o, const float* __restrict__ rays_d,
    const float* __restrict__ t_rand,
    const float* __restrict__ W1, const float* __restrict__ b1,
    const float* __restrict__ b2, const float* __restrict__ b3,
    const float* __restrict__ Wd, const float* __restrict__ bd,
    const float* __restrict__ W4, const float* __restrict__ b4,
    const float* __restrict__ W5, const float* __restrict__ b5,
    const u16* __restrict__ wpack, float* __restrict__ out) {
  __shared__ u16   act[64 * 256];    // 32 KB, XOR-swizzled slots
  __shared__ float zv[64];
  __shared__ float dist[64];
  __shared__ float dens[64];
  __shared__ float rgbL[64 * 4];
  __shared__ float vdirL[4];
  __shared__ float w5L[384];
  __shared__ float b5L[4];

  const int t = threadIdx.x;
  const int lane = t & 63;
  const int wv = t >> 6;        // 0..3
  const int quad = lane >> 4;
  const int l15 = lane & 15;
  const int ray = blockIdx.x;
  const int m0 = l15, m1 = l15 + 16, m2 = l15 + 32, m3 = l15 + 48;

  // ---- setup ----
  if (t < 64) {
    int j = t;
    float fj = (float)j;
    float zj = 0.5f + 2.0f * (fj / 63.0f);
    float lower = (j == 0)  ? zj : 0.5f * (zj + (0.5f + 2.0f * ((fj - 1.0f) / 63.0f)));
    float upper = (j == 63) ? zj : 0.5f * (zj + (0.5f + 2.0f * ((fj + 1.0f) / 63.0f)));
    float tr = t_rand[ray * 64 + j];
    zv[j] = lower + (upper - lower) * tr;
    dens[j] = 0.f;                    // accumulated via atomics in L3 epilogue
  } else {
    int idx = t - 64;                 // 0..191
    w5L[idx] = W5[idx];
    w5L[idx + 192] = W5[idx + 192];
  }
  if (t < 3) b5L[t] = b5[t];
  if (t == 3) b5L[3] = bd[0];
  if (t == 0) {
    float dx = rays_d[ray * 3 + 0];
    float dy = rays_d[ray * 3 + 1];
    float dz = rays_d[ray * 3 + 2];
    float nrm = sqrtf(dx * dx + dy * dy + dz * dz) + 1e-8f;
    vdirL[0] = dx / nrm; vdirL[1] = dy / nrm; vdirL[2] = dz / nrm;
  }
  __syncthreads();

  if (t < 64) dist[t] = (t < 63) ? (zv[t + 1] - zv[t]) : 1e10f;

  // ---- layer 1: h1 = relu(pts@W1 + b1) -> act (pure vector ops) ----
  {
    int m = t >> 2, p = t & 3;
    float zm = zv[m];
    float px = rays_o[ray * 3 + 0] + rays_d[ray * 3 + 0] * zm;
    float py = rays_o[ray * 3 + 1] + rays_d[ray * 3 + 1] * zm;
    float pz = rays_o[ray * 3 + 2] + rays_d[ray * 3 + 2] * zm;
#pragma unroll
    for (int kk = 0; kk < 64; kk += 8) {
      int k0 = p * 64 + kk;
      f32x4 bva = *(const f32x4*)(b1 + k0);
      f32x4 bvb = *(const f32x4*)(b1 + k0 + 4);
      f32x4 w0a = *(const f32x4*)(W1 + k0);
      f32x4 w0b = *(const f32x4*)(W1 + k0 + 4);
      f32x4 w1a = *(const f32x4*)(W1 + 256 + k0);
      f32x4 w1b = *(const f32x4*)(W1 + 256 + k0 + 4);
      f32x4 w2a = *(const f32x4*)(W1 + 512 + k0);
      f32x4 w2b = *(const f32x4*)(W1 + 512 + k0 + 4);
      f32x4 sa = bva + px * w0a + py * w1a + pz * w2a;
      f32x4 sb = bvb + px * w0b + py * w1b + pz * w2b;
      uint32x4 pk;
      pk[0] = cvtpk(fmaxf(sa[0], 0.f), fmaxf(sa[1], 0.f));
      pk[1] = cvtpk(fmaxf(sa[2], 0.f), fmaxf(sa[3], 0.f));
      pk[2] = cvtpk(fmaxf(sb[0], 0.f), fmaxf(sb[1], 0.f));
      pk[3] = cvtpk(fmaxf(sb[2], 0.f), fmaxf(sb[3], 0.f));
      int u = (k0 >> 3) ^ (m & 31);
      *(uint32x4*)(act + m * 256 + u * 8) = pk;
    }
  }
  __syncthreads();

  // ---- layers 2 & 3: h = relu(h@W + b), K=256, N=256, B bursts from L2 ----
  // Wave wv owns col-tiles nt = wv*4..wv*4+3. L==1 also accumulates density.
#pragma unroll 1
  for (int L = 0; L < 2; L++) {
    const u16* wB = wpack + L * 65536;
    const float* bb = (L == 0) ? b2 : b3;
    // fragment bases: col-tile c base = wB + (wv*4+c)*4096 elems, +lane*8
    const u16* bc0 = wB + (wv * 4 + 0) * 4096 + lane * 8;
    const u16* bc1 = wB + (wv * 4 + 1) * 4096 + lane * 8;
    const u16* bc2 = wB + (wv * 4 + 2) * 4096 + lane * 8;
    const u16* bc3 = wB + (wv * 4 + 3) * 4096 + lane * 8;
    f32x4 c00 = ZER4, c01 = ZER4, c02 = ZER4, c03 = ZER4;
    f32x4 c10 = ZER4, c11 = ZER4, c12 = ZER4, c13 = ZER4;
    f32x4 c20 = ZER4, c21 = ZER4, c22 = ZER4, c23 = ZER4;
    f32x4 c30 = ZER4, c31 = ZER4, c32 = ZER4, c33 = ZER4;
#pragma unroll
    for (int kc = 0; kc < 8; kc++) KSTEP4(kc);
    __syncthreads();               // all act reads done before in-place rewrite
    {
      int ng0 = wv * 64 + l15;
      float bi0 = bb[ng0], bi1 = bb[ng0 + 16], bi2 = bb[ng0 + 32], bi3 = bb[ng0 + 48];
      float wd0 = Wd[ng0], wd1 = Wd[ng0 + 16], wd2 = Wd[ng0 + 32], wd3 = Wd[ng0 + 48];
      float dp[16];
#pragma unroll
      for (int i = 0; i < 16; i++) dp[i] = 0.f;
      EPICD(c00, 0, ng0, bi0, wd0); EPICD(c10, 1, ng0, bi0, wd0);
      EPICD(c20, 2, ng0, bi0, wd0); EPICD(c30, 3, ng0, bi0, wd0);
      EPICD(c01, 0, ng0 + 16, bi1, wd1); EPICD(c11, 1, ng0 + 16, bi1, wd1);
      EPICD(c21, 2, ng0 + 16, bi1, wd1); EPICD(c31, 3, ng0 + 16, bi1, wd1);
      EPICD(c02, 0, ng0 + 32, bi2, wd2); EPICD(c12, 1, ng0 + 32, bi2, wd2);
      EPICD(c22, 2, ng0 + 32, bi2, wd2); EPICD(c32, 3, ng0 + 32, bi2, wd2);
      EPICD(c03, 0, ng0 + 48, bi3, wd3); EPICD(c13, 1, ng0 + 48, bi3, wd3);
      EPICD(c23, 2, ng0 + 48, bi3, wd3); EPICD(c33, 3, ng0 + 48, bi3, wd3);
      if (L == 1) {
        // reduce dp across the 16 lanes of this quad-group (xor within l15)
#pragma unroll
        for (int i = 0; i < 16; i++) {
          float v = dp[i];
          v += __shfl_xor(v, 1);
          v += __shfl_xor(v, 2);
          v += __shfl_xor(v, 4);
          v += __shfl_xor(v, 8);
          dp[i] = v;
        }
        if (l15 == 0) {
#pragma unroll
          for (int i = 0; i < 16; i++) {
            int row = (i >> 2) * 16 + quad * 4 + (i & 3);
            atomicAdd(&dens[row], dp[i]);
          }
        }
      }
    }
    __syncthreads();
  }

  // ---- layer 4: h4 = relu(h3@W4[:256] + vdir@W4[256:259] + b4), N=128 ----
  {
    const u16* wB = wpack + 131072;
    const u16* bc0 = wB + (wv * 2 + 0) * 4096 + lane * 8;
    const u16* bc1 = wB + (wv * 2 + 1) * 4096 + lane * 8;
    f32x4 c00 = ZER4, c01 = ZER4;
    f32x4 c10 = ZER4, c11 = ZER4;
    f32x4 c20 = ZER4, c21 = ZER4;
    f32x4 c30 = ZER4, c31 = ZER4;
#pragma unroll
    for (int kc = 0; kc < 8; kc++) KSTEP2(kc);
    __syncthreads();               // all h3 reads done before rewrite
    {
      float v0 = vdirL[0], v1 = vdirL[1], v2 = vdirL[2];
      int ng0 = wv * 32 + l15;
      float ad0 = b4[ng0] + v0 * W4[32768 + ng0] + v1 * W4[32896 + ng0] + v2 * W4[33024 + ng0];
      int ng1 = ng0 + 16;
      float ad1 = b4[ng1] + v0 * W4[32768 + ng1] + v1 * W4[32896 + ng1] + v2 * W4[33024 + ng1];
      EPIC(c00, 0, ng0, ad0); EPIC(c10, 1, ng0, ad0);
      EPIC(c20, 2, ng0, ad0); EPIC(c30, 3, ng0, ad0);
      EPIC(c01, 0, ng1, ad1); EPIC(c11, 1, ng1, ad1);
      EPIC(c21, 2, ng1, ad1); EPIC(c31, 3, ng1, ad1);
    }
  }
  __syncthreads();

  // ---- rgb = sigmoid(h4@W5 + b5) ----
  {
    int m = t >> 2, p = t & 3;
    float s0 = 0.f, s1 = 0.f, s2 = 0.f;
#pragma unroll
    for (int kk = 0; kk < 32; kk += 8) {
      int k0 = p * 32 + kk;
      short8 h = *(const short8*)(act + m * 256 + (((k0 >> 3) ^ (m & 31)) << 3));
#pragma unroll
      for (int j = 0; j < 8; j++) {
        float hv = bf2f((u16)h[j]);
        int k = k0 + j;
        s0 += hv * w5L[k * 3 + 0];
        s1 += hv * w5L[k * 3 + 1];
        s2 += hv * w5L[k * 3 + 2];
      }
    }
    s0 += __shfl_xor(s0, 1); s0 += __shfl_xor(s0, 2);
    s1 += __shfl_xor(s1, 1); s1 += __shfl_xor(s1, 2);
    s2 += __shfl_xor(s2, 1); s2 += __shfl_xor(s2, 2);
    if (p == 0) {
      rgbL[m * 4 + 0] = 1.f / (1.f + __expf(-(s0 + b5L[0])));
      rgbL[m * 4 + 1] = 1.f / (1.f + __expf(-(s1 + b5L[1])));
      rgbL[m * 4 + 2] = 1.f / (1.f + __expf(-(s2 + b5L[2])));
    }
  }
  __syncthreads();

  // ---- alpha compositing: wave 0 handles the block's single ray ----
  if (t < 64) {
    int j = t;
    float alpha = 1.f - __expf(-fmaxf(dens[j] + b5L[3], 0.f) * dist[j]);
    float v = 1.f - alpha + 1e-10f;
    float pscan = v;
#pragma unroll
    for (int d = 1; d < 64; d <<= 1) {
      float o = __shfl_up(pscan, d);
      if (j >= d) pscan *= o;
    }
    float T = __shfl_up(pscan, 1);
    if (j == 0) T = 1.f;
    float w = alpha * T;
    float r0 = w * rgbL[j * 4 + 0];
    float r1 = w * rgbL[j * 4 + 1];
    float r2 = w * rgbL[j * 4 + 2];
    float dp = w * zv[j];
    float ac = w;
#pragma unroll
    for (int d = 32; d; d >>= 1) {
      r0 += __shfl_down(r0, d);
      r1 += __shfl_down(r1, d);
      r2 += __shfl_down(r2, d);
      dp += __shfl_down(dp, d);
      ac += __shfl_down(ac, d);
    }
    if (j == 0) {
      float bg = 1.f - ac;
      out[ray * 3 + 0] = r0 + bg;
      out[ray * 3 + 1] = r1 + bg;
      out[ray * 3 + 2] = r2 + bg;
      out[NRAYS * 3 + ray] = dp;
      out[NRAYS * 4 + ray] = ac;
    }
  }
}

extern "C" void kernel_launch(void* const* d_in, const int* in_sizes, int n_in,
                              void* d_out, int out_size, void* d_ws, size_t ws_size,
                              hipStream_t stream) {
  const float* rays_o = (const float*)d_in[0];
  const float* rays_d = (const float*)d_in[1];
  const float* t_rand = (const float*)d_in[2];
  const float* W1 = (const float*)d_in[3];
  const float* b1 = (const float*)d_in[4];
  const float* W2 = (const float*)d_in[5];
  const float* b2 = (const float*)d_in[6];
  const float* W3 = (const float*)d_in[7];
  const float* b3 = (const float*)d_in[8];
  const float* Wd = (const float*)d_in[9];
  const float* bd = (const float*)d_in[10];
  const float* W4 = (const float*)d_in[11];
  const float* b4 = (const float*)d_in[12];
  const float* W5 = (const float*)d_in[13];
  const float* b5 = (const float*)d_in[14];
  u16* wpack = (u16*)d_ws;
  float* out = (float*)d_out;

  pack_weights<<<640, 256, 0, stream>>>(W2, W3, W4, wpack);
  nerf_fused<<<NRAYS, 256, 0, stream>>>(rays_o, rays_d, t_rand, W1, b1, b2, b3,
                                        Wd, bd, W4, b4, W5, b5, wpack, out);
}

// Round 6
// 232.530 us; speedup vs baseline: 3.0458x; 1.3109x over previous
//
#include <hip/hip_runtime.h>
#include <stdint.h>

// R12: phase-chain trims inside the proven (256,2)/16-acc envelope (R11=244us).
//   1. Double-buffered act (A<->B, +32KB LDS, 73KB total x2 blocks = 146KB):
//      epilogue writes go to the OTHER buffer -> the 3 pre-epilogue WAR
//      barriers in L2/L3/L4 are deleted (9 -> 6 barriers), and epilogue DS
//      writes overlap other waves' K-loop ds_reads/MFMA.
//   2. W1/b1 staged in LDS once (4KB, (k+p)-skewed conflict-free layout):
//      kills ~256KB/block of redundant L2 broadcast traffic in L1; each col's
//      4 coefficients (3 W rows + bias) arrive in ONE ds_read_b128.
//   3. L2/L3 peeled: L2 uses plain EPIC (R11 ran density FMAs for both layers;
//      64 dead FMA/thread removed), L3 uses EPICD + fused density.
// Tripwire: FETCH ~2.5MB / WRITE ~0.4MB / VGPR ~124 (envelope intact).
// Predict dur 244 -> 210-225us. If >=235 clean: barrier overhead isn't the
// residual -> next round tries (256,3) + unroll-2 K-loops (live ~110).

#define NRAYS 4096

typedef unsigned short u16;
typedef __attribute__((ext_vector_type(8))) short short8;
typedef __attribute__((ext_vector_type(4))) float f32x4;
typedef __attribute__((ext_vector_type(4))) unsigned int uint32x4;

__device__ __forceinline__ u16 f2bf(float f) {
  union { float f; uint32_t i; } v; v.f = f;
  return (u16)((v.i + 0x7FFFu + ((v.i >> 16) & 1u)) >> 16);
}
__device__ __forceinline__ float bf2f(u16 u) {
  union { uint32_t i; float f; } v; v.i = ((uint32_t)u) << 16; return v.f;
}
// packed fp32->bf16 (RNE), lo -> bits 15:0, hi -> bits 31:16 (bit-identical to f2bf)
__device__ __forceinline__ uint32_t cvtpk(float lo, float hi) {
  uint32_t r;
  asm("v_cvt_pk_bf16_f32 %0, %1, %2" : "=v"(r) : "v"(lo), "v"(hi));
  return r;
}

// fragment-contiguous index for W^T: element (n, k) of a [N][K=256] tile ->
// block (nt = n>>4, kq = k>>5), lane = ((k>>3)&3)*16 + (n&15), elem j = k&7.
// Wave load at (nt,kq) = 64 lanes x 16B = 1KB contiguous.
__device__ __forceinline__ int fragidx(int n, int k) {
  return ((((n >> 4) * 8 + (k >> 5)) * 64 + ((k >> 3) & 3) * 16 + (n & 15)) << 3) + (k & 7);
}

// ---------------- weight transpose + fp32->bf16 convert into workspace ----------------
// ws (bf16 elems): W2f @0 (65536), W3f @65536, W4f @131072 (32768)
__global__ void pack_weights(const float* __restrict__ W2, const float* __restrict__ W3,
                             const float* __restrict__ W4, u16* __restrict__ ws) {
  int idx = blockIdx.x * 256 + threadIdx.x;   // grid covers exactly 163840
  float v;
  int dst;
  if (idx < 65536) {
    int k = idx >> 8, n = idx & 255;          // W2 row-major [k][n]
    v = W2[idx];
    dst = fragidx(n, k);
  } else if (idx < 131072) {
    int o = idx - 65536, k = o >> 8, n = o & 255;
    v = W3[o];
    dst = 65536 + fragidx(n, k);
  } else {
    int o = idx - 131072, k = o >> 7, n = o & 127;  // W4 row-major [k][128]
    v = W4[o];
    dst = 131072 + fragidx(n, k);
  }
  ws[dst] = f2bf(v);
}

#define MFMA __builtin_amdgcn_mfma_f32_16x16x32_bf16
#define ZER4 (f32x4){0.f, 0.f, 0.f, 0.f}

// one K-step (kq = 0..7) of the 4-col-tile GEMM reading ACT: 4 B bursts (1KB),
// 4 A LDS reads, 16 MFMA.
#define KSTEP4(kq_, ACT) do {                                                \
    const int kq = (kq_);                                                    \
    short8 bv0 = *(const short8*)(bc0 + kq * 512);                           \
    short8 bv1 = *(const short8*)(bc1 + kq * 512);                           \
    short8 bv2 = *(const short8*)(bc2 + kq * 512);                           \
    short8 bv3 = *(const short8*)(bc3 + kq * 512);                           \
    const int sq = kq * 4 + quad;                                            \
    short8 av0 = *(const short8*)((ACT) + m0 * 256 + ((sq ^ (m0 & 31)) << 3)); \
    short8 av1 = *(const short8*)((ACT) + m1 * 256 + ((sq ^ (m1 & 31)) << 3)); \
    short8 av2 = *(const short8*)((ACT) + m2 * 256 + ((sq ^ (m2 & 31)) << 3)); \
    short8 av3 = *(const short8*)((ACT) + m3 * 256 + ((sq ^ (m3 & 31)) << 3)); \
    c00 = MFMA(av0, bv0, c00, 0, 0, 0); c10 = MFMA(av1, bv0, c10, 0, 0, 0);  \
    c20 = MFMA(av2, bv0, c20, 0, 0, 0); c30 = MFMA(av3, bv0, c30, 0, 0, 0);  \
    c01 = MFMA(av0, bv1, c01, 0, 0, 0); c11 = MFMA(av1, bv1, c11, 0, 0, 0);  \
    c21 = MFMA(av2, bv1, c21, 0, 0, 0); c31 = MFMA(av3, bv1, c31, 0, 0, 0);  \
    c02 = MFMA(av0, bv2, c02, 0, 0, 0); c12 = MFMA(av1, bv2, c12, 0, 0, 0);  \
    c22 = MFMA(av2, bv2, c22, 0, 0, 0); c32 = MFMA(av3, bv2, c32, 0, 0, 0);  \
    c03 = MFMA(av0, bv3, c03, 0, 0, 0); c13 = MFMA(av1, bv3, c13, 0, 0, 0);  \
    c23 = MFMA(av2, bv3, c23, 0, 0, 0); c33 = MFMA(av3, bv3, c33, 0, 0, 0);  \
  } while (0)

// one K-step of the 2-col-tile GEMM (layer 4) reading ACT
#define KSTEP2(kq_, ACT) do {                                                \
    const int kq = (kq_);                                                    \
    short8 bv0 = *(const short8*)(bc0 + kq * 512);                           \
    short8 bv1 = *(const short8*)(bc1 + kq * 512);                           \
    const int sq = kq * 4 + quad;                                            \
    short8 av0 = *(const short8*)((ACT) + m0 * 256 + ((sq ^ (m0 & 31)) << 3)); \
    short8 av1 = *(const short8*)((ACT) + m1 * 256 + ((sq ^ (m1 & 31)) << 3)); \
    short8 av2 = *(const short8*)((ACT) + m2 * 256 + ((sq ^ (m2 & 31)) << 3)); \
    short8 av3 = *(const short8*)((ACT) + m3 * 256 + ((sq ^ (m3 & 31)) << 3)); \
    c00 = MFMA(av0, bv0, c00, 0, 0, 0); c10 = MFMA(av1, bv0, c10, 0, 0, 0);  \
    c20 = MFMA(av2, bv0, c20, 0, 0, 0); c30 = MFMA(av3, bv0, c30, 0, 0, 0);  \
    c01 = MFMA(av0, bv1, c01, 0, 0, 0); c11 = MFMA(av1, bv1, c11, 0, 0, 0);  \
    c21 = MFMA(av2, bv1, c21, 0, 0, 0); c31 = MFMA(av3, bv1, c31, 0, 0, 0);  \
  } while (0)

// store one 16x16 C-tile (f32x4 CV), row-tile mt, column ng, into swizzled ACT
#define EPIC(CV, mt, ng, addv, ACT) do {                                     \
    int su_ = ((ng) >> 3), so_ = ((ng) & 7);                                 \
    float f0_ = fmaxf((CV)[0] + (addv), 0.f);                                \
    float f1_ = fmaxf((CV)[1] + (addv), 0.f);                                \
    float f2_ = fmaxf((CV)[2] + (addv), 0.f);                                \
    float f3_ = fmaxf((CV)[3] + (addv), 0.f);                                \
    uint32_t p01_ = cvtpk(f0_, f1_), p23_ = cvtpk(f2_, f3_);                 \
    int mmb_ = (mt) * 16 + quad * 4;                                         \
    (ACT)[(mmb_ + 0) * 256 + ((su_ ^ ((mmb_ + 0) & 31)) << 3) + so_] = (u16)p01_;         \
    (ACT)[(mmb_ + 1) * 256 + ((su_ ^ ((mmb_ + 1) & 31)) << 3) + so_] = (u16)(p01_ >> 16); \
    (ACT)[(mmb_ + 2) * 256 + ((su_ ^ ((mmb_ + 2) & 31)) << 3) + so_] = (u16)p23_;         \
    (ACT)[(mmb_ + 3) * 256 + ((su_ ^ ((mmb_ + 3) & 31)) << 3) + so_] = (u16)(p23_ >> 16); \
  } while (0)

// EPIC + density partial accumulate: dp[mt*4+r] += relu(c+b) * Wd[ng]
#define EPICD(CV, mt, ng, addv, wdv, ACT) do {                               \
    int su_ = ((ng) >> 3), so_ = ((ng) & 7);                                 \
    float f0_ = fmaxf((CV)[0] + (addv), 0.f);                                \
    float f1_ = fmaxf((CV)[1] + (addv), 0.f);                                \
    float f2_ = fmaxf((CV)[2] + (addv), 0.f);                                \
    float f3_ = fmaxf((CV)[3] + (addv), 0.f);                                \
    dp[(mt) * 4 + 0] += f0_ * (wdv);                                         \
    dp[(mt) * 4 + 1] += f1_ * (wdv);                                         \
    dp[(mt) * 4 + 2] += f2_ * (wdv);                                         \
    dp[(mt) * 4 + 3] += f3_ * (wdv);                                         \
    uint32_t p01_ = cvtpk(f0_, f1_), p23_ = cvtpk(f2_, f3_);                 \
    int mmb_ = (mt) * 16 + quad * 4;                                         \
    (ACT)[(mmb_ + 0) * 256 + ((su_ ^ ((mmb_ + 0) & 31)) << 3) + so_] = (u16)p01_;         \
    (ACT)[(mmb_ + 1) * 256 + ((su_ ^ ((mmb_ + 1) & 31)) << 3) + so_] = (u16)(p01_ >> 16); \
    (ACT)[(mmb_ + 2) * 256 + ((su_ ^ ((mmb_ + 2) & 31)) << 3) + so_] = (u16)p23_;         \
    (ACT)[(mmb_ + 3) * 256 + ((su_ ^ ((mmb_ + 3) & 31)) << 3) + so_] = (u16)(p23_ >> 16); \
  } while (0)

__global__ void __launch_bounds__(256, 2) nerf_fused(
    const float* __restrict__ rays_o, const float* __restrict__ rays_d,
    const float* __restrict__ t_rand,
    const float* __restrict__ W1, const float* __restrict__ b1,
    const float* __restrict__ b2, const float* __restrict__ b3,
    const float* __restrict__ Wd, const float* __restrict__ bd,
    const float* __restrict__ W4, const float* __restrict__ b4,
    const float* __restrict__ W5, const float* __restrict__ b5,
    const u16* __restrict__ wpack, float* __restrict__ out) {
  __shared__ u16   actA[64 * 256];   // 32 KB, XOR-swizzled slots (ping)
  __shared__ u16   actB[64 * 256];   // 32 KB (pong)
  __shared__ float w1L[1040];        // 4 KB: (k+p)-skewed [W1r0,W1r1,W1r2,b1] per col
  __shared__ float zv[64];
  __shared__ float dist[64];
  __shared__ float dens[64];
  __shared__ float rgbL[64 * 4];
  __shared__ float vdirL[4];
  __shared__ float w5L[384];
  __shared__ float b5L[4];

  const int t = threadIdx.x;
  const int lane = t & 63;
  const int wv = t >> 6;        // 0..3
  const int quad = lane >> 4;
  const int l15 = lane & 15;
  const int ray = blockIdx.x;
  const int m0 = l15, m1 = l15 + 16, m2 = l15 + 32, m3 = l15 + 48;

  // ---- setup ----
  if (t < 64) {
    int j = t;
    float fj = (float)j;
    float zj = 0.5f + 2.0f * (fj / 63.0f);
    float lower = (j == 0)  ? zj : 0.5f * (zj + (0.5f + 2.0f * ((fj - 1.0f) / 63.0f)));
    float upper = (j == 63) ? zj : 0.5f * (zj + (0.5f + 2.0f * ((fj + 1.0f) / 63.0f)));
    float tr = t_rand[ray * 64 + j];
    zv[j] = lower + (upper - lower) * tr;
    dens[j] = 0.f;                    // accumulated via atomics in L3 epilogue
  } else {
    int idx = t - 64;                 // 0..191
    w5L[idx] = W5[idx];
    w5L[idx + 192] = W5[idx + 192];
  }
  // W1/b1 -> LDS, skewed: col k lives at float offset (k + (k>>6))*4
  {
    int base = (t + (t >> 6)) * 4;
    w1L[base + 0] = W1[t];
    w1L[base + 1] = W1[256 + t];
    w1L[base + 2] = W1[512 + t];
    w1L[base + 3] = b1[t];
  }
  if (t < 3) b5L[t] = b5[t];
  if (t == 3) b5L[3] = bd[0];
  if (t == 0) {
    float dx = rays_d[ray * 3 + 0];
    float dy = rays_d[ray * 3 + 1];
    float dz = rays_d[ray * 3 + 2];
    float nrm = sqrtf(dx * dx + dy * dy + dz * dz) + 1e-8f;
    vdirL[0] = dx / nrm; vdirL[1] = dy / nrm; vdirL[2] = dz / nrm;
  }
  __syncthreads();                                          // barrier 1

  if (t < 64) dist[t] = (t < 63) ? (zv[t + 1] - zv[t]) : 1e10f;

  // ---- layer 1: h1 = relu(pts@W1 + b1) -> actA (coeffs from LDS) ----
  {
    int m = t >> 2, p = t & 3;
    float zm = zv[m];
    float px = rays_o[ray * 3 + 0] + rays_d[ray * 3 + 0] * zm;
    float py = rays_o[ray * 3 + 1] + rays_d[ray * 3 + 1] * zm;
    float pz = rays_o[ray * 3 + 2] + rays_d[ray * 3 + 2] * zm;
#pragma unroll 1
    for (int kk = 0; kk < 64; kk += 8) {
      float r[8];
#pragma unroll
      for (int j = 0; j < 8; j++) {
        int k = p * 64 + kk + j;
        f32x4 w = *(const f32x4*)(w1L + (k + p) * 4);
        r[j] = fmaxf(w[3] + px * w[0] + py * w[1] + pz * w[2], 0.f);
      }
      uint32x4 pk;
      pk[0] = cvtpk(r[0], r[1]);
      pk[1] = cvtpk(r[2], r[3]);
      pk[2] = cvtpk(r[4], r[5]);
      pk[3] = cvtpk(r[6], r[7]);
      int k0 = p * 64 + kk;
      int u = (k0 >> 3) ^ (m & 31);
      *(uint32x4*)(actA + m * 256 + u * 8) = pk;
    }
  }
  __syncthreads();                                          // barrier 2

  // ---- layer 2: h2 = relu(h1@W2 + b2) : reads actA, writes actB ----
  {
    const u16* bc0 = wpack + (wv * 4 + 0) * 4096 + lane * 8;
    const u16* bc1 = wpack + (wv * 4 + 1) * 4096 + lane * 8;
    const u16* bc2 = wpack + (wv * 4 + 2) * 4096 + lane * 8;
    const u16* bc3 = wpack + (wv * 4 + 3) * 4096 + lane * 8;
    f32x4 c00 = ZER4, c01 = ZER4, c02 = ZER4, c03 = ZER4;
    f32x4 c10 = ZER4, c11 = ZER4, c12 = ZER4, c13 = ZER4;
    f32x4 c20 = ZER4, c21 = ZER4, c22 = ZER4, c23 = ZER4;
    f32x4 c30 = ZER4, c31 = ZER4, c32 = ZER4, c33 = ZER4;
#pragma unroll
    for (int kc = 0; kc < 8; kc++) KSTEP4(kc, actA);
    // no pre-epilogue barrier: writes go to actB, reads were from actA
    int ng0 = wv * 64 + l15;
    float bi0 = b2[ng0], bi1 = b2[ng0 + 16], bi2 = b2[ng0 + 32], bi3 = b2[ng0 + 48];
    EPIC(c00, 0, ng0, bi0, actB); EPIC(c10, 1, ng0, bi0, actB);
    EPIC(c20, 2, ng0, bi0, actB); EPIC(c30, 3, ng0, bi0, actB);
    EPIC(c01, 0, ng0 + 16, bi1, actB); EPIC(c11, 1, ng0 + 16, bi1, actB);
    EPIC(c21, 2, ng0 + 16, bi1, actB); EPIC(c31, 3, ng0 + 16, bi1, actB);
    EPIC(c02, 0, ng0 + 32, bi2, actB); EPIC(c12, 1, ng0 + 32, bi2, actB);
    EPIC(c22, 2, ng0 + 32, bi2, actB); EPIC(c32, 3, ng0 + 32, bi2, actB);
    EPIC(c03, 0, ng0 + 48, bi3, actB); EPIC(c13, 1, ng0 + 48, bi3, actB);
    EPIC(c23, 2, ng0 + 48, bi3, actB); EPIC(c33, 3, ng0 + 48, bi3, actB);
  }
  __syncthreads();                                          // barrier 3

  // ---- layer 3: h3 = relu(h2@W3 + b3) + fused density : reads actB, writes actA ----
  {
    const u16* wB = wpack + 65536;
    const u16* bc0 = wB + (wv * 4 + 0) * 4096 + lane * 8;
    const u16* bc1 = wB + (wv * 4 + 1) * 4096 + lane * 8;
    const u16* bc2 = wB + (wv * 4 + 2) * 4096 + lane * 8;
    const u16* bc3 = wB + (wv * 4 + 3) * 4096 + lane * 8;
    f32x4 c00 = ZER4, c01 = ZER4, c02 = ZER4, c03 = ZER4;
    f32x4 c10 = ZER4, c11 = ZER4, c12 = ZER4, c13 = ZER4;
    f32x4 c20 = ZER4, c21 = ZER4, c22 = ZER4, c23 = ZER4;
    f32x4 c30 = ZER4, c31 = ZER4, c32 = ZER4, c33 = ZER4;
#pragma unroll
    for (int kc = 0; kc < 8; kc++) KSTEP4(kc, actB);
    int ng0 = wv * 64 + l15;
    float bi0 = b3[ng0], bi1 = b3[ng0 + 16], bi2 = b3[ng0 + 32], bi3 = b3[ng0 + 48];
    float wd0 = Wd[ng0], wd1 = Wd[ng0 + 16], wd2 = Wd[ng0 + 32], wd3 = Wd[ng0 + 48];
    float dp[16];
#pragma unroll
    for (int i = 0; i < 16; i++) dp[i] = 0.f;
    EPICD(c00, 0, ng0, bi0, wd0, actA); EPICD(c10, 1, ng0, bi0, wd0, actA);
    EPICD(c20, 2, ng0, bi0, wd0, actA); EPICD(c30, 3, ng0, bi0, wd0, actA);
    EPICD(c01, 0, ng0 + 16, bi1, wd1, actA); EPICD(c11, 1, ng0 + 16, bi1, wd1, actA);
    EPICD(c21, 2, ng0 + 16, bi1, wd1, actA); EPICD(c31, 3, ng0 + 16, bi1, wd1, actA);
    EPICD(c02, 0, ng0 + 32, bi2, wd2, actA); EPICD(c12, 1, ng0 + 32, bi2, wd2, actA);
    EPICD(c22, 2, ng0 + 32, bi2, wd2, actA); EPICD(c32, 3, ng0 + 32, bi2, wd2, actA);
    EPICD(c03, 0, ng0 + 48, bi3, wd3, actA); EPICD(c13, 1, ng0 + 48, bi3, wd3, actA);
    EPICD(c23, 2, ng0 + 48, bi3, wd3, actA); EPICD(c33, 3, ng0 + 48, bi3, wd3, actA);
    // reduce dp across the 16 lanes of this quad-group
#pragma unroll
    for (int i = 0; i < 16; i++) {
      float v = dp[i];
      v += __shfl_xor(v, 1);
      v += __shfl_xor(v, 2);
      v += __shfl_xor(v, 4);
      v += __shfl_xor(v, 8);
      dp[i] = v;
    }
    if (l15 == 0) {
#pragma unroll
      for (int i = 0; i < 16; i++) {
        int row = (i >> 2) * 16 + quad * 4 + (i & 3);
        atomicAdd(&dens[row], dp[i]);
      }
    }
  }
  __syncthreads();                                          // barrier 4

  // ---- layer 4: h4 = relu(h3@W4[:256] + vdir@W4[256:259] + b4), N=128 ----
  // reads actA, writes actB
  {
    const u16* wB = wpack + 131072;
    const u16* bc0 = wB + (wv * 2 + 0) * 4096 + lane * 8;
    const u16* bc1 = wB + (wv * 2 + 1) * 4096 + lane * 8;
    f32x4 c00 = ZER4, c01 = ZER4;
    f32x4 c10 = ZER4, c11 = ZER4;
    f32x4 c20 = ZER4, c21 = ZER4;
    f32x4 c30 = ZER4, c31 = ZER4;
#pragma unroll
    for (int kc = 0; kc < 8; kc++) KSTEP2(kc, actA);
    float v0 = vdirL[0], v1 = vdirL[1], v2 = vdirL[2];
    int ng0 = wv * 32 + l15;
    float ad0 = b4[ng0] + v0 * W4[32768 + ng0] + v1 * W4[32896 + ng0] + v2 * W4[33024 + ng0];
    int ng1 = ng0 + 16;
    float ad1 = b4[ng1] + v0 * W4[32768 + ng1] + v1 * W4[32896 + ng1] + v2 * W4[33024 + ng1];
    EPIC(c00, 0, ng0, ad0, actB); EPIC(c10, 1, ng0, ad0, actB);
    EPIC(c20, 2, ng0, ad0, actB); EPIC(c30, 3, ng0, ad0, actB);
    EPIC(c01, 0, ng1, ad1, actB); EPIC(c11, 1, ng1, ad1, actB);
    EPIC(c21, 2, ng1, ad1, actB); EPIC(c31, 3, ng1, ad1, actB);
  }
  __syncthreads();                                          // barrier 5

  // ---- rgb = sigmoid(h4@W5 + b5) : reads actB ----
  {
    int m = t >> 2, p = t & 3;
    float s0 = 0.f, s1 = 0.f, s2 = 0.f;
#pragma unroll
    for (int kk = 0; kk < 32; kk += 8) {
      int k0 = p * 32 + kk;
      short8 h = *(const short8*)(actB + m * 256 + (((k0 >> 3) ^ (m & 31)) << 3));
#pragma unroll
      for (int j = 0; j < 8; j++) {
        float hv = bf2f((u16)h[j]);
        int k = k0 + j;
        s0 += hv * w5L[k * 3 + 0];
        s1 += hv * w5L[k * 3 + 1];
        s2 += hv * w5L[k * 3 + 2];
      }
    }
    s0 += __shfl_xor(s0, 1); s0 += __shfl_xor(s0, 2);
    s1 += __shfl_xor(s1, 1); s1 += __shfl_xor(s1, 2);
    s2 += __shfl_xor(s2, 1); s2 += __shfl_xor(s2, 2);
    if (p == 0) {
      rgbL[m * 4 + 0] = 1.f / (1.f + __expf(-(s0 + b5L[0])));
      rgbL[m * 4 + 1] = 1.f / (1.f + __expf(-(s1 + b5L[1])));
      rgbL[m * 4 + 2] = 1.f / (1.f + __expf(-(s2 + b5L[2])));
    }
  }
  __syncthreads();                                          // barrier 6

  // ---- alpha compositing: wave 0 handles the block's single ray ----
  if (t < 64) {
    int j = t;
    float alpha = 1.f - __expf(-fmaxf(dens[j] + b5L[3], 0.f) * dist[j]);
    float v = 1.f - alpha + 1e-10f;
    float pscan = v;
#pragma unroll
    for (int d = 1; d < 64; d <<= 1) {
      float o = __shfl_up(pscan, d);
      if (j >= d) pscan *= o;
    }
    float T = __shfl_up(pscan, 1);
    if (j == 0) T = 1.f;
    float w = alpha * T;
    float r0 = w * rgbL[j * 4 + 0];
    float r1 = w * rgbL[j * 4 + 1];
    float r2 = w * rgbL[j * 4 + 2];
    float dp = w * zv[j];
    float ac = w;
#pragma unroll
    for (int d = 32; d; d >>= 1) {
      r0 += __shfl_down(r0, d);
      r1 += __shfl_down(r1, d);
      r2 += __shfl_down(r2, d);
      dp += __shfl_down(dp, d);
      ac += __shfl_down(ac, d);
    }
    if (j == 0) {
      float bg = 1.f - ac;
      out[ray * 3 + 0] = r0 + bg;
      out[ray * 3 + 1] = r1 + bg;
      out[ray * 3 + 2] = r2 + bg;
      out[NRAYS * 3 + ray] = dp;
      out[NRAYS * 4 + ray] = ac;
    }
  }
}

extern "C" void kernel_launch(void* const* d_in, const int* in_sizes, int n_in,
                              void* d_out, int out_size, void* d_ws, size_t ws_size,
                              hipStream_t stream) {
  const float* rays_o = (const float*)d_in[0];
  const float* rays_d = (const float*)d_in[1];
  const float* t_rand = (const float*)d_in[2];
  const float* W1 = (const float*)d_in[3];
  const float* b1 = (const float*)d_in[4];
  const float* W2 = (const float*)d_in[5];
  const float* b2 = (const float*)d_in[6];
  const float* W3 = (const float*)d_in[7];
  const float* b3 = (const float*)d_in[8];
  const float* Wd = (const float*)d_in[9];
  const float* bd = (const float*)d_in[10];
  const float* W4 = (const float*)d_in[11];
  const float* b4 = (const float*)d_in[12];
  const float* W5 = (const float*)d_in[13];
  const float* b5 = (const float*)d_in[14];
  u16* wpack = (u16*)d_ws;
  float* out = (float*)d_out;

  pack_weights<<<640, 256, 0, stream>>>(W2, W3, W4, wpack);
  nerf_fused<<<NRAYS, 256, 0, stream>>>(rays_o, rays_d, t_rand, W1, b1, b2, b3,
                                        Wd, bd, W4, b4, W5, b5, wpack, out);
}

// Round 7
// 216.542 us; speedup vs baseline: 3.2707x; 1.0738x over previous
//
#include <hip/hip_runtime.h>
#include <stdint.h>

// R13: delete the remaining latency chains (R12 = 171us kernel).
//   1. rgb via MFMA (wave-split row-tiles): W5 packed as zero-padded 16-col
//      fragment tile; 4 MFMA + 4 ds_read per wave replaces 96 FMA + 24
//      ds_read + 18 bpermute serial phase.
//   2. density via MFMA in L4's K-loop: Wd packed as padded fragment; A-frags
//      already loaded -> +1 B-load +4 MFMA per kstep; wave0 stores dens[]
//      directly. Deletes EPICD (64 FMA + 64 shfl + 16 atomicAdd + init).
//   3. cross-barrier B prefetch: L2's full B-set (128 regs) loaded at kernel
//      top (completes under setup+L1; peak ~210 < 256 budget); L3 kq0-3 and
//      L4 kq0-1 + frag tiles prefetched before their barriers (vmcnt drain
//      at s_barrier completes them during the barrier wait).
//   4. bias/vdir loads hoisted to GEMM-block tops.
// Numerics: density/rgb now via bf16 MFMA -> absmax may drift to ~0.03.
// Tripwire: FETCH ~7.5MB / WRITE ~10MB (no new spill). Predict 171 -> ~150us.
// If >=165 clean: chain-trimming plateau -> 2-ray/block (M=128) next.

#define NRAYS 4096

typedef unsigned short u16;
typedef __attribute__((ext_vector_type(8))) short short8;
typedef __attribute__((ext_vector_type(4))) float f32x4;
typedef __attribute__((ext_vector_type(4))) unsigned int uint32x4;

__device__ __forceinline__ u16 f2bf(float f) {
  union { float f; uint32_t i; } v; v.f = f;
  return (u16)((v.i + 0x7FFFu + ((v.i >> 16) & 1u)) >> 16);
}
__device__ __forceinline__ float bf2f(u16 u) {
  union { uint32_t i; float f; } v; v.i = ((uint32_t)u) << 16; return v.f;
}
// packed fp32->bf16 (RNE), lo -> bits 15:0, hi -> bits 31:16 (bit-identical to f2bf)
__device__ __forceinline__ uint32_t cvtpk(float lo, float hi) {
  uint32_t r;
  asm("v_cvt_pk_bf16_f32 %0, %1, %2" : "=v"(r) : "v"(lo), "v"(hi));
  return r;
}

// fragment-contiguous index for W^T: element (n, k) of an [N][K] tile ->
// block (nt = n>>4, kq = k>>5), lane = ((k>>3)&3)*16 + (n&15), elem j = k&7.
// Wave load at (nt,kq) = 64 lanes x 16B = 1KB contiguous.
__device__ __forceinline__ int fragidx(int n, int k) {
  return ((((n >> 4) * 8 + (k >> 5)) * 64 + ((k >> 3) & 3) * 16 + (n & 15)) << 3) + (k & 7);
}

// ---------------- weight transpose + fp32->bf16 convert into workspace ----------------
// ws (bf16 elems): W2f @0 (65536), W3f @65536 (65536), W4f @131072 (32768),
//                  Wd-pad @163840 (4096: [256K][16N], col0=Wd),
//                  W5-pad @167936 (2048: [128K][16N], cols0-2=W5)
__global__ void pack_weights(const float* __restrict__ W2, const float* __restrict__ W3,
                             const float* __restrict__ W4, const float* __restrict__ Wd,
                             const float* __restrict__ W5, u16* __restrict__ ws) {
  int idx = blockIdx.x * 256 + threadIdx.x;   // grid covers exactly 169984
  float v;
  int dst;
  if (idx < 65536) {
    int k = idx >> 8, n = idx & 255;          // W2 row-major [k][n]
    v = W2[idx];
    dst = fragidx(n, k);
  } else if (idx < 131072) {
    int o = idx - 65536, k = o >> 8, n = o & 255;
    v = W3[o];
    dst = 65536 + fragidx(n, k);
  } else if (idx < 163840) {
    int o = idx - 131072, k = o >> 7, n = o & 127;  // W4 row-major [k][128]
    v = W4[o];
    dst = 131072 + fragidx(n, k);
  } else if (idx < 167936) {
    int o = idx - 163840, k = o >> 4, n = o & 15;   // Wd [256][1] padded to 16 cols
    v = (n == 0) ? Wd[k] : 0.f;
    dst = 163840 + fragidx(n, k);
  } else {
    int o = idx - 167936, k = o >> 4, n = o & 15;   // W5 [128][3] padded to 16 cols
    v = (n < 3) ? W5[k * 3 + n] : 0.f;
    dst = 167936 + fragidx(n, k);
  }
  ws[dst] = f2bf(v);
}

#define MFMA __builtin_amdgcn_mfma_f32_16x16x32_bf16
#define ZER4 (f32x4){0.f, 0.f, 0.f, 0.f}

// declare + load the 4 A row-tile fragments for k-slice SQ from ACT
#define LDA4(ACT, SQ)                                                          \
    short8 av0 = *(const short8*)((ACT) + m0 * 256 + (((SQ) ^ (m0 & 31)) << 3)); \
    short8 av1 = *(const short8*)((ACT) + m1 * 256 + (((SQ) ^ (m1 & 31)) << 3)); \
    short8 av2 = *(const short8*)((ACT) + m2 * 256 + (((SQ) ^ (m2 & 31)) << 3)); \
    short8 av3 = *(const short8*)((ACT) + m3 * 256 + (((SQ) ^ (m3 & 31)) << 3))

// 16 MFMA: 4 row-tiles (av0..av3) x 4 B col-tiles (args)
#define MF16v(B0, B1, B2_, B3_) do {                                         \
    c00 = MFMA(av0, B0, c00, 0, 0, 0); c10 = MFMA(av1, B0, c10, 0, 0, 0);    \
    c20 = MFMA(av2, B0, c20, 0, 0, 0); c30 = MFMA(av3, B0, c30, 0, 0, 0);    \
    c01 = MFMA(av0, B1, c01, 0, 0, 0); c11 = MFMA(av1, B1, c11, 0, 0, 0);    \
    c21 = MFMA(av2, B1, c21, 0, 0, 0); c31 = MFMA(av3, B1, c31, 0, 0, 0);    \
    c02 = MFMA(av0, B2_, c02, 0, 0, 0); c12 = MFMA(av1, B2_, c12, 0, 0, 0);  \
    c22 = MFMA(av2, B2_, c22, 0, 0, 0); c32 = MFMA(av3, B2_, c32, 0, 0, 0);  \
    c03 = MFMA(av0, B3_, c03, 0, 0, 0); c13 = MFMA(av1, B3_, c13, 0, 0, 0);  \
    c23 = MFMA(av2, B3_, c23, 0, 0, 0); c33 = MFMA(av3, B3_, c33, 0, 0, 0);  \
  } while (0)

// store one 16x16 C-tile (f32x4 CV), row-tile mt, column ng, into swizzled ACT
#define EPIC(CV, mt, ng, addv, ACT) do {                                     \
    int su_ = ((ng) >> 3), so_ = ((ng) & 7);                                 \
    float f0_ = fmaxf((CV)[0] + (addv), 0.f);                                \
    float f1_ = fmaxf((CV)[1] + (addv), 0.f);                                \
    float f2_ = fmaxf((CV)[2] + (addv), 0.f);                                \
    float f3_ = fmaxf((CV)[3] + (addv), 0.f);                                \
    uint32_t p01_ = cvtpk(f0_, f1_), p23_ = cvtpk(f2_, f3_);                 \
    int mmb_ = (mt) * 16 + quad * 4;                                         \
    (ACT)[(mmb_ + 0) * 256 + ((su_ ^ ((mmb_ + 0) & 31)) << 3) + so_] = (u16)p01_;         \
    (ACT)[(mmb_ + 1) * 256 + ((su_ ^ ((mmb_ + 1) & 31)) << 3) + so_] = (u16)(p01_ >> 16); \
    (ACT)[(mmb_ + 2) * 256 + ((su_ ^ ((mmb_ + 2) & 31)) << 3) + so_] = (u16)p23_;         \
    (ACT)[(mmb_ + 3) * 256 + ((su_ ^ ((mmb_ + 3) & 31)) << 3) + so_] = (u16)(p23_ >> 16); \
  } while (0)

__global__ void __launch_bounds__(256, 2) nerf_fused(
    const float* __restrict__ rays_o, const float* __restrict__ rays_d,
    const float* __restrict__ t_rand,
    const float* __restrict__ W1, const float* __restrict__ b1,
    const float* __restrict__ b2, const float* __restrict__ b3,
    const float* __restrict__ bd,
    const float* __restrict__ W4, const float* __restrict__ b4,
    const float* __restrict__ b5,
    const u16* __restrict__ wpack, float* __restrict__ out) {
  __shared__ u16   actA[64 * 256];   // 32 KB, XOR-swizzled slots (ping)
  __shared__ u16   actB[64 * 256];   // 32 KB (pong)
  __shared__ float w1L[1040];        // 4 KB: (k+p)-skewed [W1r0,W1r1,W1r2,b1] per col
  __shared__ float zv[64];
  __shared__ float dist[64];
  __shared__ float dens[64];
  __shared__ float rgbL[64 * 4];
  __shared__ float vdirL[4];
  __shared__ float b5L[4];

  const int t = threadIdx.x;
  const int lane = t & 63;
  const int wv = t >> 6;        // 0..3
  const int quad = lane >> 4;
  const int l15 = lane & 15;
  const int ray = blockIdx.x;
  const int m0 = l15, m1 = l15 + 16, m2 = l15 + 32, m3 = l15 + 48;

  // ---- L2 B full prefetch: issued first, completes under setup+L1 ----
  short8 B2a[8], B2b[8], B2c[8], B2d[8];
  {
    const u16* q0 = wpack + (wv * 4 + 0) * 4096 + lane * 8;
    const u16* q1 = wpack + (wv * 4 + 1) * 4096 + lane * 8;
    const u16* q2 = wpack + (wv * 4 + 2) * 4096 + lane * 8;
    const u16* q3 = wpack + (wv * 4 + 3) * 4096 + lane * 8;
#pragma unroll
    for (int kq = 0; kq < 8; kq++) {
      B2a[kq] = *(const short8*)(q0 + kq * 512);
      B2b[kq] = *(const short8*)(q1 + kq * 512);
      B2c[kq] = *(const short8*)(q2 + kq * 512);
      B2d[kq] = *(const short8*)(q3 + kq * 512);
    }
  }

  // ---- setup ----
  if (t < 64) {
    int j = t;
    float fj = (float)j;
    float zj = 0.5f + 2.0f * (fj / 63.0f);
    float lower = (j == 0)  ? zj : 0.5f * (zj + (0.5f + 2.0f * ((fj - 1.0f) / 63.0f)));
    float upper = (j == 63) ? zj : 0.5f * (zj + (0.5f + 2.0f * ((fj + 1.0f) / 63.0f)));
    float tr = t_rand[ray * 64 + j];
    zv[j] = lower + (upper - lower) * tr;
  }
  // W1/b1 -> LDS, skewed: col k lives at float offset (k + (k>>6))*4
  {
    int base = (t + (t >> 6)) * 4;
    w1L[base + 0] = W1[t];
    w1L[base + 1] = W1[256 + t];
    w1L[base + 2] = W1[512 + t];
    w1L[base + 3] = b1[t];
  }
  if (t < 3) b5L[t] = b5[t];
  if (t == 3) b5L[3] = bd[0];
  if (t == 0) {
    float dx = rays_d[ray * 3 + 0];
    float dy = rays_d[ray * 3 + 1];
    float dz = rays_d[ray * 3 + 2];
    float nrm = sqrtf(dx * dx + dy * dy + dz * dz) + 1e-8f;
    vdirL[0] = dx / nrm; vdirL[1] = dy / nrm; vdirL[2] = dz / nrm;
  }
  __syncthreads();                                          // barrier 1

  if (t < 64) dist[t] = (t < 63) ? (zv[t + 1] - zv[t]) : 1e10f;

  // ---- layer 1: h1 = relu(pts@W1 + b1) -> actA (coeffs from LDS) ----
  {
    int m = t >> 2, p = t & 3;
    float zm = zv[m];
    float px = rays_o[ray * 3 + 0] + rays_d[ray * 3 + 0] * zm;
    float py = rays_o[ray * 3 + 1] + rays_d[ray * 3 + 1] * zm;
    float pz = rays_o[ray * 3 + 2] + rays_d[ray * 3 + 2] * zm;
#pragma unroll 1
    for (int kk = 0; kk < 64; kk += 8) {
      float r[8];
#pragma unroll
      for (int j = 0; j < 8; j++) {
        int k = p * 64 + kk + j;
        f32x4 w = *(const f32x4*)(w1L + (k + p) * 4);
        r[j] = fmaxf(w[3] + px * w[0] + py * w[1] + pz * w[2], 0.f);
      }
      uint32x4 pk;
      pk[0] = cvtpk(r[0], r[1]);
      pk[1] = cvtpk(r[2], r[3]);
      pk[2] = cvtpk(r[4], r[5]);
      pk[3] = cvtpk(r[6], r[7]);
      int k0 = p * 64 + kk;
      int u = (k0 >> 3) ^ (m & 31);
      *(uint32x4*)(actA + m * 256 + u * 8) = pk;
    }
  }
  __syncthreads();                                          // barrier 2

  short8 B3a[4], B3b[4], B3c[4], B3d[4];     // L3 kq0-3 prefetch (filled in L2)

  // ---- layer 2: h2 = relu(h1@W2 + b2) : reads actA, writes actB ----
  {
    int ng0 = wv * 64 + l15;
    float bi0 = b2[ng0], bi1 = b2[ng0 + 16], bi2 = b2[ng0 + 32], bi3 = b2[ng0 + 48];
    f32x4 c00 = ZER4, c01 = ZER4, c02 = ZER4, c03 = ZER4;
    f32x4 c10 = ZER4, c11 = ZER4, c12 = ZER4, c13 = ZER4;
    f32x4 c20 = ZER4, c21 = ZER4, c22 = ZER4, c23 = ZER4;
    f32x4 c30 = ZER4, c31 = ZER4, c32 = ZER4, c33 = ZER4;
#pragma unroll
    for (int kq = 0; kq < 8; kq++) {
      LDA4(actA, kq * 4 + quad);
      MF16v(B2a[kq], B2b[kq], B2c[kq], B2d[kq]);
    }
    // prefetch L3 B kq0-3 (lands during epilogue + barrier drain)
    {
      const u16* r0 = wpack + 65536 + (wv * 4 + 0) * 4096 + lane * 8;
      const u16* r1 = wpack + 65536 + (wv * 4 + 1) * 4096 + lane * 8;
      const u16* r2 = wpack + 65536 + (wv * 4 + 2) * 4096 + lane * 8;
      const u16* r3 = wpack + 65536 + (wv * 4 + 3) * 4096 + lane * 8;
#pragma unroll
      for (int kq = 0; kq < 4; kq++) {
        B3a[kq] = *(const short8*)(r0 + kq * 512);
        B3b[kq] = *(const short8*)(r1 + kq * 512);
        B3c[kq] = *(const short8*)(r2 + kq * 512);
        B3d[kq] = *(const short8*)(r3 + kq * 512);
      }
    }
    EPIC(c00, 0, ng0, bi0, actB); EPIC(c10, 1, ng0, bi0, actB);
    EPIC(c20, 2, ng0, bi0, actB); EPIC(c30, 3, ng0, bi0, actB);
    EPIC(c01, 0, ng0 + 16, bi1, actB); EPIC(c11, 1, ng0 + 16, bi1, actB);
    EPIC(c21, 2, ng0 + 16, bi1, actB); EPIC(c31, 3, ng0 + 16, bi1, actB);
    EPIC(c02, 0, ng0 + 32, bi2, actB); EPIC(c12, 1, ng0 + 32, bi2, actB);
    EPIC(c22, 2, ng0 + 32, bi2, actB); EPIC(c32, 3, ng0 + 32, bi2, actB);
    EPIC(c03, 0, ng0 + 48, bi3, actB); EPIC(c13, 1, ng0 + 48, bi3, actB);
    EPIC(c23, 2, ng0 + 48, bi3, actB); EPIC(c33, 3, ng0 + 48, bi3, actB);
  }
  __syncthreads();                                          // barrier 3

  short8 L4a[2], L4b[2], L4d[2];             // L4 kq0-1 prefetch (filled in L3)

  // ---- layer 3: h3 = relu(h2@W3 + b3) : reads actB, writes actA ----
  {
    int ng0 = wv * 64 + l15;
    float bi0 = b3[ng0], bi1 = b3[ng0 + 16], bi2 = b3[ng0 + 32], bi3 = b3[ng0 + 48];
    const u16* r0 = wpack + 65536 + (wv * 4 + 0) * 4096 + lane * 8;
    const u16* r1 = wpack + 65536 + (wv * 4 + 1) * 4096 + lane * 8;
    const u16* r2 = wpack + 65536 + (wv * 4 + 2) * 4096 + lane * 8;
    const u16* r3 = wpack + 65536 + (wv * 4 + 3) * 4096 + lane * 8;
    f32x4 c00 = ZER4, c01 = ZER4, c02 = ZER4, c03 = ZER4;
    f32x4 c10 = ZER4, c11 = ZER4, c12 = ZER4, c13 = ZER4;
    f32x4 c20 = ZER4, c21 = ZER4, c22 = ZER4, c23 = ZER4;
    f32x4 c30 = ZER4, c31 = ZER4, c32 = ZER4, c33 = ZER4;
#pragma unroll
    for (int kq = 0; kq < 8; kq++) {
      short8 b0, b1v, b2v, b3v;
      if (kq < 4) { b0 = B3a[kq]; b1v = B3b[kq]; b2v = B3c[kq]; b3v = B3d[kq]; }
      else {
        b0 = *(const short8*)(r0 + kq * 512);
        b1v = *(const short8*)(r1 + kq * 512);
        b2v = *(const short8*)(r2 + kq * 512);
        b3v = *(const short8*)(r3 + kq * 512);
      }
      LDA4(actB, kq * 4 + quad);
      MF16v(b0, b1v, b2v, b3v);
    }
    // prefetch L4 B kq0-1 + density-frag kq0-1
    {
      const u16* s0 = wpack + 131072 + (wv * 2 + 0) * 4096 + lane * 8;
      const u16* s1 = wpack + 131072 + (wv * 2 + 1) * 4096 + lane * 8;
      const u16* sD = wpack + 163840 + lane * 8;
#pragma unroll
      for (int kq = 0; kq < 2; kq++) {
        L4a[kq] = *(const short8*)(s0 + kq * 512);
        L4b[kq] = *(const short8*)(s1 + kq * 512);
        L4d[kq] = *(const short8*)(sD + kq * 512);
      }
    }
    EPIC(c00, 0, ng0, bi0, actA); EPIC(c10, 1, ng0, bi0, actA);
    EPIC(c20, 2, ng0, bi0, actA); EPIC(c30, 3, ng0, bi0, actA);
    EPIC(c01, 0, ng0 + 16, bi1, actA); EPIC(c11, 1, ng0 + 16, bi1, actA);
    EPIC(c21, 2, ng0 + 16, bi1, actA); EPIC(c31, 3, ng0 + 16, bi1, actA);
    EPIC(c02, 0, ng0 + 32, bi2, actA); EPIC(c12, 1, ng0 + 32, bi2, actA);
    EPIC(c22, 2, ng0 + 32, bi2, actA); EPIC(c32, 3, ng0 + 32, bi2, actA);
    EPIC(c03, 0, ng0 + 48, bi3, actA); EPIC(c13, 1, ng0 + 48, bi3, actA);
    EPIC(c23, 2, ng0 + 48, bi3, actA); EPIC(c33, 3, ng0 + 48, bi3, actA);
  }
  __syncthreads();                                          // barrier 4

  short8 W5f[4];                             // rgb B-frag prefetch (filled in L4)

  // ---- layer 4: h4 = relu(h3@W4 + vdir-term + b4), N=128; + fused density ----
  // reads actA, writes actB; density = h3@Wd as extra MFMA column (wave0 stores)
  {
    float v0 = vdirL[0], v1 = vdirL[1], v2 = vdirL[2];
    int ng0 = wv * 32 + l15;
    int ng1 = ng0 + 16;
    float ad0 = b4[ng0] + v0 * W4[32768 + ng0] + v1 * W4[32896 + ng0] + v2 * W4[33024 + ng0];
    float ad1 = b4[ng1] + v0 * W4[32768 + ng1] + v1 * W4[32896 + ng1] + v2 * W4[33024 + ng1];
    const u16* s0 = wpack + 131072 + (wv * 2 + 0) * 4096 + lane * 8;
    const u16* s1 = wpack + 131072 + (wv * 2 + 1) * 4096 + lane * 8;
    const u16* sD = wpack + 163840 + lane * 8;
    f32x4 c00 = ZER4, c01 = ZER4;
    f32x4 c10 = ZER4, c11 = ZER4;
    f32x4 c20 = ZER4, c21 = ZER4;
    f32x4 c30 = ZER4, c31 = ZER4;
    f32x4 c40 = ZER4, c41 = ZER4, c42 = ZER4, c43 = ZER4;   // density
#pragma unroll
    for (int kq = 0; kq < 8; kq++) {
      short8 b0 = (kq < 2) ? L4a[kq] : *(const short8*)(s0 + kq * 512);
      short8 b1v = (kq < 2) ? L4b[kq] : *(const short8*)(s1 + kq * 512);
      short8 bD = (kq < 2) ? L4d[kq] : *(const short8*)(sD + kq * 512);
      LDA4(actA, kq * 4 + quad);
      c00 = MFMA(av0, b0, c00, 0, 0, 0); c10 = MFMA(av1, b0, c10, 0, 0, 0);
      c20 = MFMA(av2, b0, c20, 0, 0, 0); c30 = MFMA(av3, b0, c30, 0, 0, 0);
      c01 = MFMA(av0, b1v, c01, 0, 0, 0); c11 = MFMA(av1, b1v, c11, 0, 0, 0);
      c21 = MFMA(av2, b1v, c21, 0, 0, 0); c31 = MFMA(av3, b1v, c31, 0, 0, 0);
      c40 = MFMA(av0, bD, c40, 0, 0, 0); c41 = MFMA(av1, bD, c41, 0, 0, 0);
      c42 = MFMA(av2, bD, c42, 0, 0, 0); c43 = MFMA(av3, bD, c43, 0, 0, 0);
    }
    // prefetch rgb W5 frag (lands during epilogue + barrier drain)
    {
      const u16* s5 = wpack + 167936 + lane * 8;
#pragma unroll
      for (int kq = 0; kq < 4; kq++) W5f[kq] = *(const short8*)(s5 + kq * 512);
    }
    EPIC(c00, 0, ng0, ad0, actB); EPIC(c10, 1, ng0, ad0, actB);
    EPIC(c20, 2, ng0, ad0, actB); EPIC(c30, 3, ng0, ad0, actB);
    EPIC(c01, 0, ng1, ad1, actB); EPIC(c11, 1, ng1, ad1, actB);
    EPIC(c21, 2, ng1, ad1, actB); EPIC(c31, 3, ng1, ad1, actB);
    // density: col 0 of the c4x tiles; wave 0, lanes l15==0 hold it
    if (wv == 0 && l15 == 0) {
#pragma unroll
      for (int r = 0; r < 4; r++) {
        dens[ 0 + quad * 4 + r] = c40[r];
        dens[16 + quad * 4 + r] = c41[r];
        dens[32 + quad * 4 + r] = c42[r];
        dens[48 + quad * 4 + r] = c43[r];
      }
    }
  }
  __syncthreads();                                          // barrier 5

  // ---- rgb = sigmoid(h4@W5 + b5) via MFMA, wave-split row-tiles ----
  {
    int mR = wv * 16 + l15;
    f32x4 cR = ZER4;
#pragma unroll
    for (int kq = 0; kq < 4; kq++) {
      short8 av = *(const short8*)(actB + mR * 256 + (((kq * 4 + quad) ^ (mR & 31)) << 3));
      cR = MFMA(av, W5f[kq], cR, 0, 0, 0);
    }
    if (l15 < 3) {
#pragma unroll
      for (int r = 0; r < 4; r++) {
        int row = wv * 16 + quad * 4 + r;
        rgbL[row * 4 + l15] = 1.f / (1.f + __expf(-(cR[r] + b5L[l15])));
      }
    }
  }
  __syncthreads();                                          // barrier 6

  // ---- alpha compositing: wave 0 handles the block's single ray ----
  if (t < 64) {
    int j = t;
    float alpha = 1.f - __expf(-fmaxf(dens[j] + b5L[3], 0.f) * dist[j]);
    float v = 1.f - alpha + 1e-10f;
    float pscan = v;
#pragma unroll
    for (int d = 1; d < 64; d <<= 1) {
      float o = __shfl_up(pscan, d);
      if (j >= d) pscan *= o;
    }
    float T = __shfl_up(pscan, 1);
    if (j == 0) T = 1.f;
    float w = alpha * T;
    float r0 = w * rgbL[j * 4 + 0];
    float r1 = w * rgbL[j * 4 + 1];
    float r2 = w * rgbL[j * 4 + 2];
    float dp = w * zv[j];
    float ac = w;
#pragma unroll
    for (int d = 32; d; d >>= 1) {
      r0 += __shfl_down(r0, d);
      r1 += __shfl_down(r1, d);
      r2 += __shfl_down(r2, d);
      dp += __shfl_down(dp, d);
      ac += __shfl_down(ac, d);
    }
    if (j == 0) {
      float bg = 1.f - ac;
      out[ray * 3 + 0] = r0 + bg;
      out[ray * 3 + 1] = r1 + bg;
      out[ray * 3 + 2] = r2 + bg;
      out[NRAYS * 3 + ray] = dp;
      out[NRAYS * 4 + ray] = ac;
    }
  }
}

extern "C" void kernel_launch(void* const* d_in, const int* in_sizes, int n_in,
                              void* d_out, int out_size, void* d_ws, size_t ws_size,
                              hipStream_t stream) {
  const float* rays_o = (const float*)d_in[0];
  const float* rays_d = (const float*)d_in[1];
  const float* t_rand = (const float*)d_in[2];
  const float* W1 = (const float*)d_in[3];
  const float* b1 = (const float*)d_in[4];
  const float* W2 = (const float*)d_in[5];
  const float* b2 = (const float*)d_in[6];
  const float* W3 = (const float*)d_in[7];
  const float* b3 = (const float*)d_in[8];
  const float* Wd = (const float*)d_in[9];
  const float* bd = (const float*)d_in[10];
  const float* W4 = (const float*)d_in[11];
  const float* b4 = (const float*)d_in[12];
  const float* W5 = (const float*)d_in[13];
  const float* b5 = (const float*)d_in[14];
  u16* wpack = (u16*)d_ws;
  float* out = (float*)d_out;

  pack_weights<<<664, 256, 0, stream>>>(W2, W3, W4, Wd, W5, wpack);
  nerf_fused<<<NRAYS, 256, 0, stream>>>(rays_o, rays_d, t_rand, W1, b1, b2, b3,
                                        bd, W4, b4, b5, wpack, out);
}